// Round 8
// baseline (577.399 us; speedup 1.0000x reference)
//
#include <hip/hip_runtime.h>

#define CDIV(a,b) (((a)+(b)-1)/(b))

typedef float f32x4 __attribute__((ext_vector_type(4)));
typedef short short8 __attribute__((ext_vector_type(8)));
typedef _Float16 h16x8 __attribute__((ext_vector_type(8)));

// ---------------- bf16 helpers (RNE) ----------------

__device__ inline unsigned short rne_bf16(float f) {
    unsigned int u = __builtin_bit_cast(unsigned int, f);
    u += 0x7FFFu + ((u >> 16) & 1u);
    return (unsigned short)(u >> 16);
}

struct BF16Pair { short hi, lo; };

__device__ inline BF16Pair split_bf16(float f) {
    unsigned short h = rne_bf16(f);
    float fh = __builtin_bit_cast(float, (unsigned int)h << 16);
    BF16Pair p;
    p.hi = (short)h;
    p.lo = (short)rne_bf16(f - fh);
    return p;
}

// ---------------- CSR build: histogram, scan, bucket-fill ----------------

__global__ void zero_int_kernel(int* p, int n) {
    int i = blockIdx.x * blockDim.x + threadIdx.x;
    if (i < n) p[i] = 0;
}

__global__ void hist_kernel(const int* __restrict__ dst, int* cnt, int E) {
    int i = blockIdx.x * blockDim.x + threadIdx.x;
    if (i < E) atomicAdd(&cnt[dst[i]], 1);
}

__global__ void dinv_kernel(const int* __restrict__ cnt, float* dinv, int n) {
    int i = blockIdx.x * blockDim.x + threadIdx.x;
    if (i < n) dinv[i] = rsqrtf((float)cnt[i] + 1.0f);
}

__global__ __launch_bounds__(512) void scan_block_kernel(const int* __restrict__ cnt,
                                                         int* rp, int* aux, int N) {
    __shared__ int s[512];
    int t = threadIdx.x;
    int i = blockIdx.x * 512 + t;
    int v = (i < N) ? cnt[i] : 0;
    s[t] = v;
    __syncthreads();
    for (int off = 1; off < 512; off <<= 1) {
        int x = (t >= off) ? s[t - off] : 0;
        __syncthreads();
        s[t] += x;
        __syncthreads();
    }
    if (i < N) rp[i] = s[t] - v;
    if (t == 511) aux[blockIdx.x] = s[511];
}

__global__ __launch_bounds__(256) void scan_aux_kernel(int* aux, int nb) {
    __shared__ int s[256];
    int t = threadIdx.x;
    int v = (t < nb) ? aux[t] : 0;
    s[t] = v;
    __syncthreads();
    for (int off = 1; off < 256; off <<= 1) {
        int x = (t >= off) ? s[t - off] : 0;
        __syncthreads();
        s[t] += x;
        __syncthreads();
    }
    if (t < nb) aux[t] = s[t] - v;
}

__global__ void scan_add_kernel(int* rp, const int* __restrict__ aux, int N, int E) {
    int i = blockIdx.x * blockDim.x + threadIdx.x;
    if (i < N) rp[i] += aux[i >> 9];
    if (i == N) rp[N] = E;
}

__global__ void copy_int_kernel(const int* __restrict__ rp, int* fill, int n) {
    int i = blockIdx.x * blockDim.x + threadIdx.x;
    if (i < n) fill[i] = rp[i];
}

// 1 edge/thread (max wave-parallel atomic chains); NT store streams col past L2.
__global__ void fill_csr_kernel(const int* __restrict__ src, const int* __restrict__ dst,
                                int* fill, int* col, int E) {
    int e = blockIdx.x * blockDim.x + threadIdx.x;
    if (e >= E) return;
    int d = dst[e];
    int s = src[e];
    int pos = atomicAdd(&fill[d], 1);
    __builtin_nontemporal_store(s, &col[pos]);
}

// ---------------- W prep: fp32 [K][F] -> split-bf16 in MFMA B-fragment order ----

template<int K, int F>
__global__ void wprep_kernel(const float* __restrict__ W, short* __restrict__ whi,
                             short* __restrict__ wlo) {
    constexpr int CB = F / 16;
    int idx = blockIdx.x * 256 + threadIdx.x;
    if (idx >= K * F) return;
    int e = idx & 7;
    int lane = (idx >> 3) & 63;
    int fc = idx >> 9;               // kb*CB + cb
    int kb = fc / CB, cb = fc % CB;
    int k = kb * 32 + (lane >> 4) * 8 + e;
    int colv = cb * 16 + (lane & 15);
    BF16Pair p = split_bf16(W[k * F + colv]);
    whi[idx] = p.hi;
    wlo[idx] = p.lo;
}

// ---------------- MFMA GEMM: H[N,F] = fp16( dinv[r] * (A[N,K] @ W[K,F]) ) --------
// AT = float (layer 1) or _Float16 (layers 2-4; split-bf16 of fp16 is exact).

template<int K, int F, typename AT>
__global__ __launch_bounds__(256) void mfma_gemm(const AT* __restrict__ A,
                                                 const short* __restrict__ Whi,
                                                 const short* __restrict__ Wlo,
                                                 const float* __restrict__ dinv,
                                                 _Float16* __restrict__ H, int N) {
    constexpr int CB = F / 16;
    constexpr int KB = K / 32;
    constexpr int MT = 2;                 // row-frags per wave
    const int tid = threadIdx.x;
    const int wid = tid >> 6, lane = tid & 63;
    const int rowf = lane & 15;
    const int kgrp = lane >> 4;
    const long long row0 = (long long)blockIdx.x * (MT * 16 * 4) + wid * (MT * 16);

    f32x4 acc[MT][CB] = {};

    for (int kb = 0; kb < KB; ++kb) {
        short8 ahi[MT], alo[MT];
#pragma unroll
        for (int mt = 0; mt < MT; ++mt) {
            long long r = row0 + mt * 16 + rowf;
            short8 h = {0,0,0,0,0,0,0,0}, l = {0,0,0,0,0,0,0,0};
            if (r < N) {
                const AT* ap = A + (size_t)r * K + kb * 32 + kgrp * 8;
                float fv[8];
                if constexpr (sizeof(AT) == 4) {
                    float4 f0 = ((const float4*)ap)[0];
                    float4 f1 = ((const float4*)ap)[1];
                    fv[0]=f0.x; fv[1]=f0.y; fv[2]=f0.z; fv[3]=f0.w;
                    fv[4]=f1.x; fv[5]=f1.y; fv[6]=f1.z; fv[7]=f1.w;
                } else {
                    h16x8 hv = *(const h16x8*)ap;
#pragma unroll
                    for (int j = 0; j < 8; ++j) fv[j] = (float)hv[j];
                }
#pragma unroll
                for (int j = 0; j < 8; ++j) {
                    BF16Pair p = split_bf16(fv[j]);
                    h[j] = p.hi;
                    l[j] = p.lo;
                }
            }
            ahi[mt] = h;
            alo[mt] = l;
        }
#pragma unroll
        for (int cb = 0; cb < CB; ++cb) {
            size_t fo = ((size_t)(kb * CB + cb) * 64 + lane) * 8;
            short8 bhi = *(const short8*)(Whi + fo);
            short8 blo = *(const short8*)(Wlo + fo);
#pragma unroll
            for (int mt = 0; mt < MT; ++mt) {
                acc[mt][cb] = __builtin_amdgcn_mfma_f32_16x16x32_bf16(ahi[mt], bhi, acc[mt][cb], 0, 0, 0);
                acc[mt][cb] = __builtin_amdgcn_mfma_f32_16x16x32_bf16(alo[mt], bhi, acc[mt][cb], 0, 0, 0);
                acc[mt][cb] = __builtin_amdgcn_mfma_f32_16x16x32_bf16(ahi[mt], blo, acc[mt][cb], 0, 0, 0);
            }
        }
    }

    // D layout: col = lane&15, row = (lane>>4)*4 + j ; scale by dinv[row], cvt fp16
    const int rsub = (lane >> 4) * 4;
#pragma unroll
    for (int mt = 0; mt < MT; ++mt) {
        long long rbase = row0 + mt * 16 + rsub;
        float dv[4];
#pragma unroll
        for (int j = 0; j < 4; ++j) dv[j] = (rbase + j < N) ? dinv[rbase + j] : 0.f;
#pragma unroll
        for (int cb = 0; cb < CB; ++cb) {
            int colv = cb * 16 + rowf;
#pragma unroll
            for (int j = 0; j < 4; ++j) {
                long long r = rbase + j;
                if (r < N) H[(size_t)r * F + colv] = (_Float16)(acc[mt][cb][j] * dv[j]);
            }
        }
    }
}

// ---------------- fused CSR aggregation (fp16 gather, fp32 accum) ----------------
// z[d] = dinv[d] * (hs[d] + sum_{s in N(d)} hs[s]) + bias  (+ReLU); OutT = fp16 or fp32.

template<int F, bool RELU, typename OutT>
__global__ __launch_bounds__(256) void agg_kernel(const _Float16* __restrict__ hs,
                                                  const int* __restrict__ rp,
                                                  const int* __restrict__ col,
                                                  const float* __restrict__ dinv,
                                                  const float* __restrict__ bias,
                                                  OutT* __restrict__ out, int N) {
    constexpr int LPN = F / 8;            // lanes per node, 16B/lane
    constexpr int NPB = 256 / LPN;
    const int tid = threadIdx.x;
    const int lane = tid % LPN;
    const int node = blockIdx.x * NPB + tid / LPN;
    if (node >= N) return;

    const int f0 = lane * 8;
    const _Float16* hbase = hs + f0;

    float acc[8];
    {
        h16x8 sv = *(const h16x8*)(hbase + (size_t)node * F);
#pragma unroll
        for (int v = 0; v < 8; ++v) acc[v] = (float)sv[v];
    }

    int e = rp[node];
    const int e1 = rp[node + 1];
    for (; e + 4 <= e1; e += 4) {
        int s0 = col[e], s1 = col[e + 1], s2 = col[e + 2], s3 = col[e + 3];
        h16x8 v0 = *(const h16x8*)(hbase + (size_t)s0 * F);
        h16x8 v1 = *(const h16x8*)(hbase + (size_t)s1 * F);
        h16x8 v2 = *(const h16x8*)(hbase + (size_t)s2 * F);
        h16x8 v3 = *(const h16x8*)(hbase + (size_t)s3 * F);
#pragma unroll
        for (int v = 0; v < 8; ++v)
            acc[v] += ((float)v0[v] + (float)v1[v]) + ((float)v2[v] + (float)v3[v]);
    }
    for (; e < e1; ++e) {
        h16x8 v0 = *(const h16x8*)(hbase + (size_t)col[e] * F);
#pragma unroll
        for (int v = 0; v < 8; ++v) acc[v] += (float)v0[v];
    }

    const float self = dinv[node];
    OutT* op = out + (size_t)node * F + f0;
    const float* bp = bias + f0;
#pragma unroll
    for (int v = 0; v < 8; ++v) {
        float r = fmaf(acc[v], self, bp[v]);
        if (RELU) r = fmaxf(r, 0.f);
        op[v] = (OutT)r;
    }
}

// ---------------- chunked aggregation (A/B experiment, layer 2 only) ----------------
// One launch per 32-feature (64B) chunk: gather slice = N*64B = 6.4MB, aims for L2 residency.

template<int F, int CF, bool RELU>
__global__ __launch_bounds__(256) void agg_chunk_kernel(const _Float16* __restrict__ hs,
                                                        const int* __restrict__ rp,
                                                        const int* __restrict__ col,
                                                        const float* __restrict__ dinv,
                                                        const float* __restrict__ bias,
                                                        _Float16* __restrict__ out,
                                                        int N, int c0) {
    constexpr int LPN = CF / 8;           // 32 feats -> 4 lanes/node
    constexpr int NPB = 256 / LPN;        // 64 nodes/block
    const int tid = threadIdx.x;
    const int lane = tid % LPN;
    const int node = blockIdx.x * NPB + tid / LPN;
    if (node >= N) return;

    const int f0 = c0 + lane * 8;
    const _Float16* hbase = hs + f0;

    float acc[8];
    {
        h16x8 sv = *(const h16x8*)(hbase + (size_t)node * F);
#pragma unroll
        for (int v = 0; v < 8; ++v) acc[v] = (float)sv[v];
    }

    int e = rp[node];
    const int e1 = rp[node + 1];
    for (; e + 4 <= e1; e += 4) {
        int s0 = col[e], s1 = col[e + 1], s2 = col[e + 2], s3 = col[e + 3];
        h16x8 v0 = *(const h16x8*)(hbase + (size_t)s0 * F);
        h16x8 v1 = *(const h16x8*)(hbase + (size_t)s1 * F);
        h16x8 v2 = *(const h16x8*)(hbase + (size_t)s2 * F);
        h16x8 v3 = *(const h16x8*)(hbase + (size_t)s3 * F);
#pragma unroll
        for (int v = 0; v < 8; ++v)
            acc[v] += ((float)v0[v] + (float)v1[v]) + ((float)v2[v] + (float)v3[v]);
    }
    for (; e < e1; ++e) {
        h16x8 v0 = *(const h16x8*)(hbase + (size_t)col[e] * F);
#pragma unroll
        for (int v = 0; v < 8; ++v) acc[v] += (float)v0[v];
    }

    const float self = dinv[node];
    _Float16* op = out + (size_t)node * F + f0;
    const float* bp = bias + f0;
#pragma unroll
    for (int v = 0; v < 8; ++v) {
        float r = fmaf(acc[v], self, bp[v]);
        if (RELU) r = fmaxf(r, 0.f);
        op[v] = (_Float16)r;
    }
}

// ---------------- launcher ----------------

extern "C" void kernel_launch(void* const* d_in, const int* in_sizes, int n_in,
                              void* d_out, int out_size, void* d_ws, size_t ws_size,
                              hipStream_t stream) {
    const float* x  = (const float*)d_in[0];
    const int*   ei = (const int*)d_in[1];
    const float* W1 = (const float*)d_in[2];
    const float* b1 = (const float*)d_in[3];
    const float* W2 = (const float*)d_in[4];
    const float* b2 = (const float*)d_in[5];
    const float* W3 = (const float*)d_in[6];
    const float* b3 = (const float*)d_in[7];
    const float* W4 = (const float*)d_in[8];
    const float* b4 = (const float*)d_in[9];

    const int N = in_sizes[0] / 256;
    const int E = in_sizes[1] / 2;
    const int* src = ei;
    const int* dst = ei + E;

    const int NB = CDIV(N, 512);

    char* base = (char*)d_ws;
    size_t o = 0;
    auto alloc = [&](size_t bytes) { char* p = base + o; o += (bytes + 255) & ~(size_t)255; return p; };
    int*   cnt  = (int*)  alloc(sizeof(int) * N);        // histogram, then bucket cursor
    int*   rp   = (int*)  alloc(sizeof(int) * (N + 1));
    int*   aux  = (int*)  alloc(sizeof(int) * 256);
    float* dinv = (float*)alloc(sizeof(float) * N);
    int*   col  = (int*)  alloc(sizeof(int) * E);
    short* w1h  = (short*)alloc(sizeof(short) * 256 * 128);
    short* w1l  = (short*)alloc(sizeof(short) * 256 * 128);
    short* w2h  = (short*)alloc(sizeof(short) * 128 * 128);
    short* w2l  = (short*)alloc(sizeof(short) * 128 * 128);
    short* w3h  = (short*)alloc(sizeof(short) * 128 * 64);
    short* w3l  = (short*)alloc(sizeof(short) * 128 * 64);
    short* w4h  = (short*)alloc(sizeof(short) * 64 * 32);
    short* w4l  = (short*)alloc(sizeof(short) * 64 * 32);
    _Float16* hsbuf = (_Float16*)alloc(sizeof(_Float16) * (size_t)N * 128);  // GEMM out (pre-scaled)
    _Float16* zsbuf = (_Float16*)alloc(sizeof(_Float16) * (size_t)N * 128);  // agg out (activation)
    float* out  = (float*)d_out;

    // --- weight prep (split-bf16, fragment-swizzled) ---
    wprep_kernel<256, 128><<<CDIV(256 * 128, 256), 256, 0, stream>>>(W1, w1h, w1l);
    wprep_kernel<128, 128><<<CDIV(128 * 128, 256), 256, 0, stream>>>(W2, w2h, w2l);
    wprep_kernel<128, 64><<<CDIV(128 * 64, 256), 256, 0, stream>>>(W3, w3h, w3l);
    wprep_kernel<64, 32><<<CDIV(64 * 32, 256), 256, 0, stream>>>(W4, w4h, w4l);

    // --- CSR build + normalization ---
    zero_int_kernel<<<CDIV(N, 256), 256, 0, stream>>>(cnt, N);
    hist_kernel<<<CDIV(E, 256), 256, 0, stream>>>(dst, cnt, E);
    dinv_kernel<<<CDIV(N, 256), 256, 0, stream>>>(cnt, dinv, N);
    scan_block_kernel<<<NB, 512, 0, stream>>>(cnt, rp, aux, N);
    scan_aux_kernel<<<1, 256, 0, stream>>>(aux, NB);
    scan_add_kernel<<<CDIV(N + 1, 256), 256, 0, stream>>>(rp, aux, N, E);
    copy_int_kernel<<<CDIV(N, 256), 256, 0, stream>>>(rp, cnt, N);
    fill_csr_kernel<<<CDIV(E, 256), 256, 0, stream>>>(src, dst, cnt, col, E);

    const int GG = CDIV(N, 128);  // gemm grid (128 rows/block)

    // --- layer 1 --- (plain agg: A-side of the experiment)
    mfma_gemm<256, 128, float><<<GG, 256, 0, stream>>>(x, w1h, w1l, dinv, hsbuf, N);
    agg_kernel<128, true, _Float16><<<CDIV(N, 16), 256, 0, stream>>>(hsbuf, rp, col, dinv, b1, zsbuf, N);

    // --- layer 2 --- (chunked agg: B-side of the experiment, 4x 32-feature launches)
    mfma_gemm<128, 128, _Float16><<<GG, 256, 0, stream>>>(zsbuf, w2h, w2l, dinv, hsbuf, N);
    for (int c0 = 0; c0 < 128; c0 += 32)
        agg_chunk_kernel<128, 32, true><<<CDIV(N, 64), 256, 0, stream>>>(hsbuf, rp, col, dinv, b2, zsbuf, N, c0);

    // --- layer 3 ---
    mfma_gemm<128, 64, _Float16><<<GG, 256, 0, stream>>>(zsbuf, w3h, w3l, dinv, hsbuf, N);
    agg_kernel<64, true, _Float16><<<CDIV(N, 32), 256, 0, stream>>>(hsbuf, rp, col, dinv, b3, zsbuf, N);

    // --- layer 4 ---
    mfma_gemm<64, 32, _Float16><<<GG, 256, 0, stream>>>(zsbuf, w4h, w4l, dinv, hsbuf, N);
    agg_kernel<32, false, float><<<CDIV(N, 64), 256, 0, stream>>>(hsbuf, rp, col, dinv, b4, out, N);
}

// Round 9
// 482.215 us; speedup vs baseline: 1.1974x; 1.1974x over previous
//
#include <hip/hip_runtime.h>

#define CDIV(a,b) (((a)+(b)-1)/(b))
#define BUK_SHIFT 10
#define EPB 16384   // edges per bucketize block

typedef float f32x4 __attribute__((ext_vector_type(4)));
typedef short short8 __attribute__((ext_vector_type(8)));
typedef _Float16 h16x8 __attribute__((ext_vector_type(8)));

// ---------------- bf16 helpers (RNE) ----------------

__device__ inline unsigned short rne_bf16(float f) {
    unsigned int u = __builtin_bit_cast(unsigned int, f);
    u += 0x7FFFu + ((u >> 16) & 1u);
    return (unsigned short)(u >> 16);
}

struct BF16Pair { short hi, lo; };

__device__ inline BF16Pair split_bf16(float f) {
    unsigned short h = rne_bf16(f);
    float fh = __builtin_bit_cast(float, (unsigned int)h << 16);
    BF16Pair p;
    p.hi = (short)h;
    p.lo = (short)rne_bf16(f - fh);
    return p;
}

// ---------------- CSR build ----------------

__global__ void zero_int_kernel(int* p, int n) {
    int i = blockIdx.x * blockDim.x + threadIdx.x;
    if (i < n) p[i] = 0;
}

__global__ void hist_kernel(const int* __restrict__ dst, int* cnt, int E) {
    int i = blockIdx.x * blockDim.x + threadIdx.x;
    if (i < E) atomicAdd(&cnt[dst[i]], 1);
}

__global__ void dinv_kernel(const int* __restrict__ cnt, float* dinv, int n) {
    int i = blockIdx.x * blockDim.x + threadIdx.x;
    if (i < n) dinv[i] = rsqrtf((float)cnt[i] + 1.0f);
}

__global__ __launch_bounds__(512) void scan_block_kernel(const int* __restrict__ cnt,
                                                         int* rp, int* aux, int N) {
    __shared__ int s[512];
    int t = threadIdx.x;
    int i = blockIdx.x * 512 + t;
    int v = (i < N) ? cnt[i] : 0;
    s[t] = v;
    __syncthreads();
    for (int off = 1; off < 512; off <<= 1) {
        int x = (t >= off) ? s[t - off] : 0;
        __syncthreads();
        s[t] += x;
        __syncthreads();
    }
    if (i < N) rp[i] = s[t] - v;
    if (t == 511) aux[blockIdx.x] = s[511];
}

__global__ __launch_bounds__(256) void scan_aux_kernel(int* aux, int nb) {
    __shared__ int s[256];
    int t = threadIdx.x;
    int v = (t < nb) ? aux[t] : 0;
    s[t] = v;
    __syncthreads();
    for (int off = 1; off < 256; off <<= 1) {
        int x = (t >= off) ? s[t - off] : 0;
        __syncthreads();
        s[t] += x;
        __syncthreads();
    }
    if (t < nb) aux[t] = s[t] - v;
}

__global__ void scan_add_kernel(int* rp, const int* __restrict__ aux, int N, int E) {
    int i = blockIdx.x * blockDim.x + threadIdx.x;
    if (i < N) rp[i] += aux[i >> 9];
    if (i == N) rp[N] = E;
}

__global__ void copy_int_kernel(const int* __restrict__ rp, int* fill, int n) {
    int i = blockIdx.x * blockDim.x + threadIdx.x;
    if (i < n) fill[i] = rp[i];
}

// --- bucketed edge sort (write-locality for fill) ---

// A1: per-block histogram over coarse dst-buckets
__global__ __launch_bounds__(256) void bkt_hist_kernel(const int* __restrict__ dst,
                                                       int* __restrict__ hcnt,
                                                       int E, int nbuk, int nblk) {
    __shared__ int lh[128];
    int t = threadIdx.x;
    for (int i = t; i < nbuk; i += 256) lh[i] = 0;
    __syncthreads();
    int base = blockIdx.x * EPB;
    int end = min(base + EPB, E);
    for (int e = base + t; e < end; e += 256)
        atomicAdd(&lh[dst[e] >> BUK_SHIFT], 1);
    __syncthreads();
    for (int i = t; i < nbuk; i += 256) hcnt[i * nblk + blockIdx.x] = lh[i];
}

// A2: single-block in-place exclusive scan of the flat [nbuk*nblk] array
__global__ __launch_bounds__(1024) void scan_flat_kernel(int* a, int n) {
    __shared__ int s[1024];
    int t = threadIdx.x;
    int per = (n + 1023) / 1024;
    int start = t * per, end = min(start + per, n);
    int sum = 0;
    for (int i = start; i < end; ++i) sum += a[i];
    s[t] = sum;
    __syncthreads();
    for (int off = 1; off < 1024; off <<= 1) {
        int x = (t >= off) ? s[t - off] : 0;
        __syncthreads();
        s[t] += x;
        __syncthreads();
    }
    int run = s[t] - sum;
    for (int i = start; i < end; ++i) { int v = a[i]; a[i] = run; run += v; }
}

// A3: scatter (dst,src) records into per-(block,bucket) private contiguous regions
__global__ __launch_bounds__(256) void bkt_scatter_kernel(const int* __restrict__ src,
                                                          const int* __restrict__ dst,
                                                          const int* __restrict__ obk,
                                                          unsigned long long* __restrict__ ebuf,
                                                          int E, int nbuk, int nblk) {
    __shared__ int cur[128];
    int t = threadIdx.x;
    for (int i = t; i < nbuk; i += 256) cur[i] = obk[i * nblk + blockIdx.x];
    __syncthreads();
    int base = blockIdx.x * EPB;
    int end = min(base + EPB, E);
    for (int e = base + t; e < end; e += 256) {
        int d = dst[e], s = src[e];
        int b = d >> BUK_SHIFT;
        int pos = atomicAdd(&cur[b], 1);
        ebuf[pos] = ((unsigned long long)(unsigned)d << 32) | (unsigned)s;
    }
}

// B: fill col from bucket-ordered records; positions fall in L2-resident windows
__global__ void fill_csr_kernel(const unsigned long long* __restrict__ ebuf,
                                int* fill, int* __restrict__ col, int E) {
    int e = blockIdx.x * blockDim.x + threadIdx.x;
    if (e >= E) return;
    unsigned long long r = ebuf[e];
    int s = (int)(unsigned)(r & 0xFFFFFFFFull);
    int d = (int)(unsigned)(r >> 32);
    int pos = atomicAdd(&fill[d], 1);
    col[pos] = s;
}

// ---------------- W prep: fp32 [K][F] -> split-bf16 in MFMA B-fragment order ----

template<int K, int F>
__global__ void wprep_kernel(const float* __restrict__ W, short* __restrict__ whi,
                             short* __restrict__ wlo) {
    constexpr int CB = F / 16;
    int idx = blockIdx.x * 256 + threadIdx.x;
    if (idx >= K * F) return;
    int e = idx & 7;
    int lane = (idx >> 3) & 63;
    int fc = idx >> 9;               // kb*CB + cb
    int kb = fc / CB, cb = fc % CB;
    int k = kb * 32 + (lane >> 4) * 8 + e;
    int colv = cb * 16 + (lane & 15);
    BF16Pair p = split_bf16(W[k * F + colv]);
    whi[idx] = p.hi;
    wlo[idx] = p.lo;
}

// ---------------- MFMA GEMM: H[N,F] = fp16( dinv[r] * (A[N,K] @ W[K,F]) ) --------

template<int K, int F, typename AT>
__global__ __launch_bounds__(256) void mfma_gemm(const AT* __restrict__ A,
                                                 const short* __restrict__ Whi,
                                                 const short* __restrict__ Wlo,
                                                 const float* __restrict__ dinv,
                                                 _Float16* __restrict__ H, int N) {
    constexpr int CB = F / 16;
    constexpr int KB = K / 32;
    constexpr int MT = 2;                 // row-frags per wave
    const int tid = threadIdx.x;
    const int wid = tid >> 6, lane = tid & 63;
    const int rowf = lane & 15;
    const int kgrp = lane >> 4;
    const long long row0 = (long long)blockIdx.x * (MT * 16 * 4) + wid * (MT * 16);

    f32x4 acc[MT][CB] = {};

    for (int kb = 0; kb < KB; ++kb) {
        short8 ahi[MT], alo[MT];
#pragma unroll
        for (int mt = 0; mt < MT; ++mt) {
            long long r = row0 + mt * 16 + rowf;
            short8 h = {0,0,0,0,0,0,0,0}, l = {0,0,0,0,0,0,0,0};
            if (r < N) {
                const AT* ap = A + (size_t)r * K + kb * 32 + kgrp * 8;
                float fv[8];
                if constexpr (sizeof(AT) == 4) {
                    float4 f0 = ((const float4*)ap)[0];
                    float4 f1 = ((const float4*)ap)[1];
                    fv[0]=f0.x; fv[1]=f0.y; fv[2]=f0.z; fv[3]=f0.w;
                    fv[4]=f1.x; fv[5]=f1.y; fv[6]=f1.z; fv[7]=f1.w;
                } else {
                    h16x8 hv = *(const h16x8*)ap;
#pragma unroll
                    for (int j = 0; j < 8; ++j) fv[j] = (float)hv[j];
                }
#pragma unroll
                for (int j = 0; j < 8; ++j) {
                    BF16Pair p = split_bf16(fv[j]);
                    h[j] = p.hi;
                    l[j] = p.lo;
                }
            }
            ahi[mt] = h;
            alo[mt] = l;
        }
#pragma unroll
        for (int cb = 0; cb < CB; ++cb) {
            size_t fo = ((size_t)(kb * CB + cb) * 64 + lane) * 8;
            short8 bhi = *(const short8*)(Whi + fo);
            short8 blo = *(const short8*)(Wlo + fo);
#pragma unroll
            for (int mt = 0; mt < MT; ++mt) {
                acc[mt][cb] = __builtin_amdgcn_mfma_f32_16x16x32_bf16(ahi[mt], bhi, acc[mt][cb], 0, 0, 0);
                acc[mt][cb] = __builtin_amdgcn_mfma_f32_16x16x32_bf16(alo[mt], bhi, acc[mt][cb], 0, 0, 0);
                acc[mt][cb] = __builtin_amdgcn_mfma_f32_16x16x32_bf16(ahi[mt], blo, acc[mt][cb], 0, 0, 0);
            }
        }
    }

    // D layout: col = lane&15, row = (lane>>4)*4 + j ; scale by dinv[row], cvt fp16
    const int rsub = (lane >> 4) * 4;
#pragma unroll
    for (int mt = 0; mt < MT; ++mt) {
        long long rbase = row0 + mt * 16 + rsub;
        float dv[4];
#pragma unroll
        for (int j = 0; j < 4; ++j) dv[j] = (rbase + j < N) ? dinv[rbase + j] : 0.f;
#pragma unroll
        for (int cb = 0; cb < CB; ++cb) {
            int colv = cb * 16 + rowf;
#pragma unroll
            for (int j = 0; j < 4; ++j) {
                long long r = rbase + j;
                if (r < N) H[(size_t)r * F + colv] = (_Float16)(acc[mt][cb][j] * dv[j]);
            }
        }
    }
}

// ---------------- fused CSR aggregation (fp16 gather, fp32 accum) ----------------

template<int F, bool RELU, typename OutT>
__global__ __launch_bounds__(256) void agg_kernel(const _Float16* __restrict__ hs,
                                                  const int* __restrict__ rp,
                                                  const int* __restrict__ col,
                                                  const float* __restrict__ dinv,
                                                  const float* __restrict__ bias,
                                                  OutT* __restrict__ out, int N) {
    constexpr int LPN = F / 8;            // lanes per node, 16B/lane
    constexpr int NPB = 256 / LPN;
    const int tid = threadIdx.x;
    const int lane = tid % LPN;
    const int node = blockIdx.x * NPB + tid / LPN;
    if (node >= N) return;

    const int f0 = lane * 8;
    const _Float16* hbase = hs + f0;

    float acc[8];
    {
        h16x8 sv = *(const h16x8*)(hbase + (size_t)node * F);
#pragma unroll
        for (int v = 0; v < 8; ++v) acc[v] = (float)sv[v];
    }

    int e = rp[node];
    const int e1 = rp[node + 1];
    for (; e + 4 <= e1; e += 4) {
        int s0 = col[e], s1 = col[e + 1], s2 = col[e + 2], s3 = col[e + 3];
        h16x8 v0 = *(const h16x8*)(hbase + (size_t)s0 * F);
        h16x8 v1 = *(const h16x8*)(hbase + (size_t)s1 * F);
        h16x8 v2 = *(const h16x8*)(hbase + (size_t)s2 * F);
        h16x8 v3 = *(const h16x8*)(hbase + (size_t)s3 * F);
#pragma unroll
        for (int v = 0; v < 8; ++v)
            acc[v] += ((float)v0[v] + (float)v1[v]) + ((float)v2[v] + (float)v3[v]);
    }
    for (; e < e1; ++e) {
        h16x8 v0 = *(const h16x8*)(hbase + (size_t)col[e] * F);
#pragma unroll
        for (int v = 0; v < 8; ++v) acc[v] += (float)v0[v];
    }

    const float self = dinv[node];
    OutT* op = out + (size_t)node * F + f0;
    const float* bp = bias + f0;
#pragma unroll
    for (int v = 0; v < 8; ++v) {
        float r = fmaf(acc[v], self, bp[v]);
        if (RELU) r = fmaxf(r, 0.f);
        op[v] = (OutT)r;
    }
}

// ---------------- launcher ----------------

extern "C" void kernel_launch(void* const* d_in, const int* in_sizes, int n_in,
                              void* d_out, int out_size, void* d_ws, size_t ws_size,
                              hipStream_t stream) {
    const float* x  = (const float*)d_in[0];
    const int*   ei = (const int*)d_in[1];
    const float* W1 = (const float*)d_in[2];
    const float* b1 = (const float*)d_in[3];
    const float* W2 = (const float*)d_in[4];
    const float* b2 = (const float*)d_in[5];
    const float* W3 = (const float*)d_in[6];
    const float* b3 = (const float*)d_in[7];
    const float* W4 = (const float*)d_in[8];
    const float* b4 = (const float*)d_in[9];

    const int N = in_sizes[0] / 256;
    const int E = in_sizes[1] / 2;
    const int* src = ei;
    const int* dst = ei + E;

    const int NB   = CDIV(N, 512);            // node-scan blocks
    const int nbuk = ((N - 1) >> BUK_SHIFT) + 1;   // <=128 for N<=131072
    const int nblk = CDIV(E, EPB);            // bucketize blocks

    char* base = (char*)d_ws;
    size_t o = 0;
    auto alloc = [&](size_t bytes) { char* p = base + o; o += (bytes + 255) & ~(size_t)255; return p; };
    int*   cnt  = (int*)  alloc(sizeof(int) * N);        // histogram, then bucket cursor
    int*   rp   = (int*)  alloc(sizeof(int) * (N + 1));
    int*   aux  = (int*)  alloc(sizeof(int) * 256);
    float* dinv = (float*)alloc(sizeof(float) * N);
    int*   col  = (int*)  alloc(sizeof(int) * E);
    int*   hcnt = (int*)  alloc(sizeof(int) * (size_t)nbuk * nblk);
    unsigned long long* ebuf = (unsigned long long*)alloc(sizeof(unsigned long long) * E);
    short* w1h  = (short*)alloc(sizeof(short) * 256 * 128);
    short* w1l  = (short*)alloc(sizeof(short) * 256 * 128);
    short* w2h  = (short*)alloc(sizeof(short) * 128 * 128);
    short* w2l  = (short*)alloc(sizeof(short) * 128 * 128);
    short* w3h  = (short*)alloc(sizeof(short) * 128 * 64);
    short* w3l  = (short*)alloc(sizeof(short) * 128 * 64);
    short* w4h  = (short*)alloc(sizeof(short) * 64 * 32);
    short* w4l  = (short*)alloc(sizeof(short) * 64 * 32);
    _Float16* hsbuf = (_Float16*)alloc(sizeof(_Float16) * (size_t)N * 128);  // GEMM out (pre-scaled)
    _Float16* zsbuf = (_Float16*)alloc(sizeof(_Float16) * (size_t)N * 128);  // agg out (activation)
    float* out  = (float*)d_out;

    // --- weight prep (split-bf16, fragment-swizzled) ---
    wprep_kernel<256, 128><<<CDIV(256 * 128, 256), 256, 0, stream>>>(W1, w1h, w1l);
    wprep_kernel<128, 128><<<CDIV(128 * 128, 256), 256, 0, stream>>>(W2, w2h, w2l);
    wprep_kernel<128, 64><<<CDIV(128 * 64, 256), 256, 0, stream>>>(W3, w3h, w3l);
    wprep_kernel<64, 32><<<CDIV(64 * 32, 256), 256, 0, stream>>>(W4, w4h, w4l);

    // --- node degree + rp scan ---
    zero_int_kernel<<<CDIV(N, 256), 256, 0, stream>>>(cnt, N);
    hist_kernel<<<CDIV(E, 256), 256, 0, stream>>>(dst, cnt, E);
    dinv_kernel<<<CDIV(N, 256), 256, 0, stream>>>(cnt, dinv, N);
    scan_block_kernel<<<NB, 512, 0, stream>>>(cnt, rp, aux, N);
    scan_aux_kernel<<<1, 256, 0, stream>>>(aux, NB);
    scan_add_kernel<<<CDIV(N + 1, 256), 256, 0, stream>>>(rp, aux, N, E);

    // --- bucketed edge sort + fill ---
    bkt_hist_kernel<<<nblk, 256, 0, stream>>>(dst, hcnt, E, nbuk, nblk);
    scan_flat_kernel<<<1, 1024, 0, stream>>>(hcnt, nbuk * nblk);
    bkt_scatter_kernel<<<nblk, 256, 0, stream>>>(src, dst, hcnt, ebuf, E, nbuk, nblk);
    copy_int_kernel<<<CDIV(N, 256), 256, 0, stream>>>(rp, cnt, N);
    fill_csr_kernel<<<CDIV(E, 256), 256, 0, stream>>>(ebuf, cnt, col, E);

    const int GG = CDIV(N, 128);  // gemm grid (128 rows/block)

    // --- layer 1 ---
    mfma_gemm<256, 128, float><<<GG, 256, 0, stream>>>(x, w1h, w1l, dinv, hsbuf, N);
    agg_kernel<128, true, _Float16><<<CDIV(N, 16), 256, 0, stream>>>(hsbuf, rp, col, dinv, b1, zsbuf, N);

    // --- layer 2 ---
    mfma_gemm<128, 128, _Float16><<<GG, 256, 0, stream>>>(zsbuf, w2h, w2l, dinv, hsbuf, N);
    agg_kernel<128, true, _Float16><<<CDIV(N, 16), 256, 0, stream>>>(hsbuf, rp, col, dinv, b2, zsbuf, N);

    // --- layer 3 ---
    mfma_gemm<128, 64, _Float16><<<GG, 256, 0, stream>>>(zsbuf, w3h, w3l, dinv, hsbuf, N);
    agg_kernel<64, true, _Float16><<<CDIV(N, 32), 256, 0, stream>>>(hsbuf, rp, col, dinv, b3, zsbuf, N);

    // --- layer 4 ---
    mfma_gemm<64, 32, _Float16><<<GG, 256, 0, stream>>>(zsbuf, w4h, w4l, dinv, hsbuf, N);
    agg_kernel<32, false, float><<<CDIV(N, 64), 256, 0, stream>>>(hsbuf, rp, col, dinv, b4, out, N);
}

// Round 10
// 472.254 us; speedup vs baseline: 1.2226x; 1.0211x over previous
//
#include <hip/hip_runtime.h>

#define CDIV(a,b) (((a)+(b)-1)/(b))
#define BUK_SHIFT 10
#define EPB 16384   // edges per bucketize block

typedef float f32x4 __attribute__((ext_vector_type(4)));
typedef short short8 __attribute__((ext_vector_type(8)));
typedef _Float16 h16x8 __attribute__((ext_vector_type(8)));

// ---------------- bf16 helpers (RNE) ----------------

__device__ inline unsigned short rne_bf16(float f) {
    unsigned int u = __builtin_bit_cast(unsigned int, f);
    u += 0x7FFFu + ((u >> 16) & 1u);
    return (unsigned short)(u >> 16);
}

struct BF16Pair { short hi, lo; };

__device__ inline BF16Pair split_bf16(float f) {
    unsigned short h = rne_bf16(f);
    float fh = __builtin_bit_cast(float, (unsigned int)h << 16);
    BF16Pair p;
    p.hi = (short)h;
    p.lo = (short)rne_bf16(f - fh);
    return p;
}

// ---------------- CSR build ----------------

__global__ void zero_int_kernel(int* p, int n) {
    int i = blockIdx.x * blockDim.x + threadIdx.x;
    if (i < n) p[i] = 0;
}

__global__ void hist_kernel(const int* __restrict__ dst, int* cnt, int E) {
    int i = blockIdx.x * blockDim.x + threadIdx.x;
    if (i < E) atomicAdd(&cnt[dst[i]], 1);
}

__global__ void dinv_kernel(const int* __restrict__ cnt, float* dinv, int n) {
    int i = blockIdx.x * blockDim.x + threadIdx.x;
    if (i < n) dinv[i] = rsqrtf((float)cnt[i] + 1.0f);
}

__global__ __launch_bounds__(512) void scan_block_kernel(const int* __restrict__ cnt,
                                                         int* rp, int* aux, int N) {
    __shared__ int s[512];
    int t = threadIdx.x;
    int i = blockIdx.x * 512 + t;
    int v = (i < N) ? cnt[i] : 0;
    s[t] = v;
    __syncthreads();
    for (int off = 1; off < 512; off <<= 1) {
        int x = (t >= off) ? s[t - off] : 0;
        __syncthreads();
        s[t] += x;
        __syncthreads();
    }
    if (i < N) rp[i] = s[t] - v;
    if (t == 511) aux[blockIdx.x] = s[511];
}

__global__ __launch_bounds__(256) void scan_aux_kernel(int* aux, int nb) {
    __shared__ int s[256];
    int t = threadIdx.x;
    int v = (t < nb) ? aux[t] : 0;
    s[t] = v;
    __syncthreads();
    for (int off = 1; off < 256; off <<= 1) {
        int x = (t >= off) ? s[t - off] : 0;
        __syncthreads();
        s[t] += x;
        __syncthreads();
    }
    if (t < nb) aux[t] = s[t] - v;
}

__global__ void scan_add_kernel(int* rp, const int* __restrict__ aux, int N, int E) {
    int i = blockIdx.x * blockDim.x + threadIdx.x;
    if (i < N) rp[i] += aux[i >> 9];
    if (i == N) rp[N] = E;
}

__global__ void copy_int_kernel(const int* __restrict__ rp, int* fill, int n) {
    int i = blockIdx.x * blockDim.x + threadIdx.x;
    if (i < n) fill[i] = rp[i];
}

// --- bucketed edge sort (write-locality for fill) ---

__global__ __launch_bounds__(256) void bkt_hist_kernel(const int* __restrict__ dst,
                                                       int* __restrict__ hcnt,
                                                       int E, int nbuk, int nblk) {
    __shared__ int lh[128];
    int t = threadIdx.x;
    for (int i = t; i < nbuk; i += 256) lh[i] = 0;
    __syncthreads();
    int base = blockIdx.x * EPB;
    int end = min(base + EPB, E);
    for (int e = base + t; e < end; e += 256)
        atomicAdd(&lh[dst[e] >> BUK_SHIFT], 1);
    __syncthreads();
    for (int i = t; i < nbuk; i += 256) hcnt[i * nblk + blockIdx.x] = lh[i];
}

__global__ __launch_bounds__(1024) void scan_flat_kernel(int* a, int n) {
    __shared__ int s[1024];
    int t = threadIdx.x;
    int per = (n + 1023) / 1024;
    int start = t * per, end = min(start + per, n);
    int sum = 0;
    for (int i = start; i < end; ++i) sum += a[i];
    s[t] = sum;
    __syncthreads();
    for (int off = 1; off < 1024; off <<= 1) {
        int x = (t >= off) ? s[t - off] : 0;
        __syncthreads();
        s[t] += x;
        __syncthreads();
    }
    int run = s[t] - sum;
    for (int i = start; i < end; ++i) { int v = a[i]; a[i] = run; run += v; }
}

__global__ __launch_bounds__(256) void bkt_scatter_kernel(const int* __restrict__ src,
                                                          const int* __restrict__ dst,
                                                          const int* __restrict__ obk,
                                                          unsigned long long* __restrict__ ebuf,
                                                          int E, int nbuk, int nblk) {
    __shared__ int cur[128];
    int t = threadIdx.x;
    for (int i = t; i < nbuk; i += 256) cur[i] = obk[i * nblk + blockIdx.x];
    __syncthreads();
    int base = blockIdx.x * EPB;
    int end = min(base + EPB, E);
    for (int e = base + t; e < end; e += 256) {
        int d = dst[e], s = src[e];
        int b = d >> BUK_SHIFT;
        int pos = atomicAdd(&cur[b], 1);
        ebuf[pos] = ((unsigned long long)(unsigned)d << 32) | (unsigned)s;
    }
}

__global__ void fill_csr_kernel(const unsigned long long* __restrict__ ebuf,
                                int* fill, int* __restrict__ col, int E) {
    int e = blockIdx.x * blockDim.x + threadIdx.x;
    if (e >= E) return;
    unsigned long long r = ebuf[e];
    int s = (int)(unsigned)(r & 0xFFFFFFFFull);
    int d = (int)(unsigned)(r >> 32);
    int pos = atomicAdd(&fill[d], 1);
    col[pos] = s;
}

// ---------------- W prep: fp32 [K][F] -> split-bf16 in MFMA B-fragment order ----

template<int K, int F>
__global__ void wprep_kernel(const float* __restrict__ W, short* __restrict__ whi,
                             short* __restrict__ wlo) {
    constexpr int CB = F / 16;
    int idx = blockIdx.x * 256 + threadIdx.x;
    if (idx >= K * F) return;
    int e = idx & 7;
    int lane = (idx >> 3) & 63;
    int fc = idx >> 9;               // kb*CB + cb
    int kb = fc / CB, cb = fc % CB;
    int k = kb * 32 + (lane >> 4) * 8 + e;
    int colv = cb * 16 + (lane & 15);
    BF16Pair p = split_bf16(W[k * F + colv]);
    whi[idx] = p.hi;
    wlo[idx] = p.lo;
}

// ---------------- MFMA GEMM: H[N,F] = fp16( dinv[r] * (A[N,K] @ W[K,F]) ) --------
// B (hi+lo fragments) double-buffered in LDS, shared by 4 waves. Raw s_barrier +
// counted waits keep next-tile global loads in flight across the barrier
// (avoids __syncthreads' vmcnt(0) drain). A rows prefetched into registers.

template<int K, int F, typename AT>
__global__ __launch_bounds__(256) void mfma_gemm(const AT* __restrict__ A,
                                                 const short* __restrict__ Whi,
                                                 const short* __restrict__ Wlo,
                                                 const float* __restrict__ dinv,
                                                 _Float16* __restrict__ H, int N) {
    constexpr int CB = F / 16;
    constexpr int KB = K / 32;
    constexpr int MT = 2;                 // row-frags per wave
    constexpr int HCH = CB * 64;          // 16B chunks per (hi or lo) stream per kb
    constexpr int CHUNKS = HCH * 2;       // always a multiple of 256
    constexpr int CPT = CHUNKS / 256;     // chunks per thread

    __shared__ __align__(16) short Bs[2][CB * 1024];   // [buf][hi: CB*512 | lo: CB*512]

    const int tid = threadIdx.x;
    const int wid = tid >> 6, lane = tid & 63;
    const int rowf = lane & 15;
    const int kgrp = lane >> 4;
    const long long row0 = (long long)blockIdx.x * (MT * 16 * 4) + wid * (MT * 16);

    f32x4 acc[MT][CB] = {};
    short8 breg[CPT];
    float fvaC[MT][8], fvaN[MT][8];

    auto stage_issue = [&](int kb) {
#pragma unroll
        for (int i = 0; i < CPT; ++i) {
            int c = tid + i * 256;
            const short* p = (c < HCH) ? (Whi + (size_t)kb * (CB * 512) + (size_t)c * 8)
                                       : (Wlo + (size_t)kb * (CB * 512) + (size_t)(c - HCH) * 8);
            breg[i] = *(const short8*)p;
        }
    };
    auto stage_write = [&](int b) {
#pragma unroll
        for (int i = 0; i < CPT; ++i) {
            int c = tid + i * 256;
            *(short8*)&Bs[b][(size_t)c * 8] = breg[i];
        }
    };
    auto a_load = [&](float (&dst)[MT][8], int kb) {
#pragma unroll
        for (int mt = 0; mt < MT; ++mt) {
            long long r = row0 + mt * 16 + rowf;
            if (r < N) {
                const AT* ap = A + (size_t)r * K + kb * 32 + kgrp * 8;
                if constexpr (sizeof(AT) == 4) {
                    float4 f0 = ((const float4*)ap)[0];
                    float4 f1 = ((const float4*)ap)[1];
                    dst[mt][0]=f0.x; dst[mt][1]=f0.y; dst[mt][2]=f0.z; dst[mt][3]=f0.w;
                    dst[mt][4]=f1.x; dst[mt][5]=f1.y; dst[mt][6]=f1.z; dst[mt][7]=f1.w;
                } else {
                    h16x8 hv = *(const h16x8*)ap;
#pragma unroll
                    for (int j = 0; j < 8; ++j) dst[mt][j] = (float)hv[j];
                }
            } else {
#pragma unroll
                for (int j = 0; j < 8; ++j) dst[mt][j] = 0.f;
            }
        }
    };

    stage_issue(0);
    a_load(fvaC, 0);

    for (int kb = 0; kb < KB; ++kb) {
        const int b = kb & 1;
        stage_write(b);                       // compiler waits vmcnt for breg's loads
        if (kb + 1 < KB) stage_issue(kb + 1); // next-tile loads fly across the barrier
        asm volatile("s_waitcnt lgkmcnt(0)" ::: "memory");  // my ds_writes visible
        __builtin_amdgcn_s_barrier();
        __builtin_amdgcn_sched_barrier(0);    // pin ds_reads below the barrier
        if (kb + 1 < KB) a_load(fvaN, kb + 1);

        short8 ahi[MT], alo[MT];
#pragma unroll
        for (int mt = 0; mt < MT; ++mt) {
#pragma unroll
            for (int j = 0; j < 8; ++j) {
                BF16Pair p = split_bf16(fvaC[mt][j]);
                ahi[mt][j] = p.hi;
                alo[mt][j] = p.lo;
            }
        }
#pragma unroll
        for (int cb = 0; cb < CB; ++cb) {
            short8 bhi = *(const short8*)&Bs[b][((size_t)cb * 64 + lane) * 8];
            short8 blo = *(const short8*)&Bs[b][CB * 512 + ((size_t)cb * 64 + lane) * 8];
#pragma unroll
            for (int mt = 0; mt < MT; ++mt) {
                acc[mt][cb] = __builtin_amdgcn_mfma_f32_16x16x32_bf16(ahi[mt], bhi, acc[mt][cb], 0, 0, 0);
                acc[mt][cb] = __builtin_amdgcn_mfma_f32_16x16x32_bf16(alo[mt], bhi, acc[mt][cb], 0, 0, 0);
                acc[mt][cb] = __builtin_amdgcn_mfma_f32_16x16x32_bf16(ahi[mt], blo, acc[mt][cb], 0, 0, 0);
            }
        }
#pragma unroll
        for (int mt = 0; mt < MT; ++mt)
#pragma unroll
            for (int j = 0; j < 8; ++j) fvaC[mt][j] = fvaN[mt][j];
    }

    // D layout: col = lane&15, row = (lane>>4)*4 + j ; scale by dinv[row], cvt fp16
    const int rsub = (lane >> 4) * 4;
#pragma unroll
    for (int mt = 0; mt < MT; ++mt) {
        long long rbase = row0 + mt * 16 + rsub;
        float dv[4];
#pragma unroll
        for (int j = 0; j < 4; ++j) dv[j] = (rbase + j < N) ? dinv[rbase + j] : 0.f;
#pragma unroll
        for (int cb = 0; cb < CB; ++cb) {
            int colv = cb * 16 + rowf;
#pragma unroll
            for (int j = 0; j < 4; ++j) {
                long long r = rbase + j;
                if (r < N) H[(size_t)r * F + colv] = (_Float16)(acc[mt][cb][j] * dv[j]);
            }
        }
    }
}

// ---------------- fused CSR aggregation (fp16 gather, fp32 accum) ----------------

template<int F, bool RELU, typename OutT>
__global__ __launch_bounds__(256) void agg_kernel(const _Float16* __restrict__ hs,
                                                  const int* __restrict__ rp,
                                                  const int* __restrict__ col,
                                                  const float* __restrict__ dinv,
                                                  const float* __restrict__ bias,
                                                  OutT* __restrict__ out, int N) {
    constexpr int LPN = F / 8;            // lanes per node, 16B/lane
    constexpr int NPB = 256 / LPN;
    const int tid = threadIdx.x;
    const int lane = tid % LPN;
    const int node = blockIdx.x * NPB + tid / LPN;
    if (node >= N) return;

    const int f0 = lane * 8;
    const _Float16* hbase = hs + f0;

    float acc[8];
    {
        h16x8 sv = *(const h16x8*)(hbase + (size_t)node * F);
#pragma unroll
        for (int v = 0; v < 8; ++v) acc[v] = (float)sv[v];
    }

    int e = rp[node];
    const int e1 = rp[node + 1];
    for (; e + 4 <= e1; e += 4) {
        int s0 = col[e], s1 = col[e + 1], s2 = col[e + 2], s3 = col[e + 3];
        h16x8 v0 = *(const h16x8*)(hbase + (size_t)s0 * F);
        h16x8 v1 = *(const h16x8*)(hbase + (size_t)s1 * F);
        h16x8 v2 = *(const h16x8*)(hbase + (size_t)s2 * F);
        h16x8 v3 = *(const h16x8*)(hbase + (size_t)s3 * F);
#pragma unroll
        for (int v = 0; v < 8; ++v)
            acc[v] += ((float)v0[v] + (float)v1[v]) + ((float)v2[v] + (float)v3[v]);
    }
    for (; e < e1; ++e) {
        h16x8 v0 = *(const h16x8*)(hbase + (size_t)col[e] * F);
#pragma unroll
        for (int v = 0; v < 8; ++v) acc[v] += (float)v0[v];
    }

    const float self = dinv[node];
    OutT* op = out + (size_t)node * F + f0;
    const float* bp = bias + f0;
#pragma unroll
    for (int v = 0; v < 8; ++v) {
        float r = fmaf(acc[v], self, bp[v]);
        if (RELU) r = fmaxf(r, 0.f);
        op[v] = (OutT)r;
    }
}

// ---------------- launcher ----------------

extern "C" void kernel_launch(void* const* d_in, const int* in_sizes, int n_in,
                              void* d_out, int out_size, void* d_ws, size_t ws_size,
                              hipStream_t stream) {
    const float* x  = (const float*)d_in[0];
    const int*   ei = (const int*)d_in[1];
    const float* W1 = (const float*)d_in[2];
    const float* b1 = (const float*)d_in[3];
    const float* W2 = (const float*)d_in[4];
    const float* b2 = (const float*)d_in[5];
    const float* W3 = (const float*)d_in[6];
    const float* b3 = (const float*)d_in[7];
    const float* W4 = (const float*)d_in[8];
    const float* b4 = (const float*)d_in[9];

    const int N = in_sizes[0] / 256;
    const int E = in_sizes[1] / 2;
    const int* src = ei;
    const int* dst = ei + E;

    const int NB   = CDIV(N, 512);
    const int nbuk = ((N - 1) >> BUK_SHIFT) + 1;
    const int nblk = CDIV(E, EPB);

    char* base = (char*)d_ws;
    size_t o = 0;
    auto alloc = [&](size_t bytes) { char* p = base + o; o += (bytes + 255) & ~(size_t)255; return p; };
    int*   cnt  = (int*)  alloc(sizeof(int) * N);
    int*   rp   = (int*)  alloc(sizeof(int) * (N + 1));
    int*   aux  = (int*)  alloc(sizeof(int) * 256);
    float* dinv = (float*)alloc(sizeof(float) * N);
    int*   col  = (int*)  alloc(sizeof(int) * E);
    int*   hcnt = (int*)  alloc(sizeof(int) * (size_t)nbuk * nblk);
    unsigned long long* ebuf = (unsigned long long*)alloc(sizeof(unsigned long long) * E);
    short* w1h  = (short*)alloc(sizeof(short) * 256 * 128);
    short* w1l  = (short*)alloc(sizeof(short) * 256 * 128);
    short* w2h  = (short*)alloc(sizeof(short) * 128 * 128);
    short* w2l  = (short*)alloc(sizeof(short) * 128 * 128);
    short* w3h  = (short*)alloc(sizeof(short) * 128 * 64);
    short* w3l  = (short*)alloc(sizeof(short) * 128 * 64);
    short* w4h  = (short*)alloc(sizeof(short) * 64 * 32);
    short* w4l  = (short*)alloc(sizeof(short) * 64 * 32);
    _Float16* hsbuf = (_Float16*)alloc(sizeof(_Float16) * (size_t)N * 128);
    _Float16* zsbuf = (_Float16*)alloc(sizeof(_Float16) * (size_t)N * 128);
    float* out  = (float*)d_out;

    // --- weight prep (split-bf16, fragment-swizzled) ---
    wprep_kernel<256, 128><<<CDIV(256 * 128, 256), 256, 0, stream>>>(W1, w1h, w1l);
    wprep_kernel<128, 128><<<CDIV(128 * 128, 256), 256, 0, stream>>>(W2, w2h, w2l);
    wprep_kernel<128, 64><<<CDIV(128 * 64, 256), 256, 0, stream>>>(W3, w3h, w3l);
    wprep_kernel<64, 32><<<CDIV(64 * 32, 256), 256, 0, stream>>>(W4, w4h, w4l);

    // --- node degree + rp scan ---
    zero_int_kernel<<<CDIV(N, 256), 256, 0, stream>>>(cnt, N);
    hist_kernel<<<CDIV(E, 256), 256, 0, stream>>>(dst, cnt, E);
    dinv_kernel<<<CDIV(N, 256), 256, 0, stream>>>(cnt, dinv, N);
    scan_block_kernel<<<NB, 512, 0, stream>>>(cnt, rp, aux, N);
    scan_aux_kernel<<<1, 256, 0, stream>>>(aux, NB);
    scan_add_kernel<<<CDIV(N + 1, 256), 256, 0, stream>>>(rp, aux, N, E);

    // --- bucketed edge sort + fill ---
    bkt_hist_kernel<<<nblk, 256, 0, stream>>>(dst, hcnt, E, nbuk, nblk);
    scan_flat_kernel<<<1, 1024, 0, stream>>>(hcnt, nbuk * nblk);
    bkt_scatter_kernel<<<nblk, 256, 0, stream>>>(src, dst, hcnt, ebuf, E, nbuk, nblk);
    copy_int_kernel<<<CDIV(N, 256), 256, 0, stream>>>(rp, cnt, N);
    fill_csr_kernel<<<CDIV(E, 256), 256, 0, stream>>>(ebuf, cnt, col, E);

    const int GG = CDIV(N, 128);  // gemm grid (128 rows/block)

    // --- layer 1 ---
    mfma_gemm<256, 128, float><<<GG, 256, 0, stream>>>(x, w1h, w1l, dinv, hsbuf, N);
    agg_kernel<128, true, _Float16><<<CDIV(N, 16), 256, 0, stream>>>(hsbuf, rp, col, dinv, b1, zsbuf, N);

    // --- layer 2 ---
    mfma_gemm<128, 128, _Float16><<<GG, 256, 0, stream>>>(zsbuf, w2h, w2l, dinv, hsbuf, N);
    agg_kernel<128, true, _Float16><<<CDIV(N, 16), 256, 0, stream>>>(hsbuf, rp, col, dinv, b2, zsbuf, N);

    // --- layer 3 ---
    mfma_gemm<128, 64, _Float16><<<GG, 256, 0, stream>>>(zsbuf, w3h, w3l, dinv, hsbuf, N);
    agg_kernel<64, true, _Float16><<<CDIV(N, 32), 256, 0, stream>>>(hsbuf, rp, col, dinv, b3, zsbuf, N);

    // --- layer 4 ---
    mfma_gemm<64, 32, _Float16><<<GG, 256, 0, stream>>>(zsbuf, w4h, w4l, dinv, hsbuf, N);
    agg_kernel<32, false, float><<<CDIV(N, 64), 256, 0, stream>>>(hsbuf, rp, col, dinv, b4, out, N);
}

// Round 11
// 413.049 us; speedup vs baseline: 1.3979x; 1.1433x over previous
//
#include <hip/hip_runtime.h>

#define CDIV(a,b) (((a)+(b)-1)/(b))
#define BUK_SHIFT 10
#define EPB 16384   // edges per bucketize block

typedef float f32x4 __attribute__((ext_vector_type(4)));
typedef short short8 __attribute__((ext_vector_type(8)));
typedef _Float16 h16x8 __attribute__((ext_vector_type(8)));

// ---------------- bf16 helpers (RNE) ----------------

__device__ inline unsigned short rne_bf16(float f) {
    unsigned int u = __builtin_bit_cast(unsigned int, f);
    u += 0x7FFFu + ((u >> 16) & 1u);
    return (unsigned short)(u >> 16);
}

struct BF16Pair { short hi, lo; };

__device__ inline BF16Pair split_bf16(float f) {
    unsigned short h = rne_bf16(f);
    float fh = __builtin_bit_cast(float, (unsigned int)h << 16);
    BF16Pair p;
    p.hi = (short)h;
    p.lo = (short)rne_bf16(f - fh);
    return p;
}

// ---------------- CSR build ----------------

__global__ void dinv_kernel(const int* __restrict__ cnt, float* dinv, int n) {
    int i = blockIdx.x * blockDim.x + threadIdx.x;
    if (i < n) dinv[i] = rsqrtf((float)cnt[i] + 1.0f);
}

__global__ __launch_bounds__(512) void scan_block_kernel(const int* __restrict__ cnt,
                                                         int* rp, int* aux, int N) {
    __shared__ int s[512];
    int t = threadIdx.x;
    int i = blockIdx.x * 512 + t;
    int v = (i < N) ? cnt[i] : 0;
    s[t] = v;
    __syncthreads();
    for (int off = 1; off < 512; off <<= 1) {
        int x = (t >= off) ? s[t - off] : 0;
        __syncthreads();
        s[t] += x;
        __syncthreads();
    }
    if (i < N) rp[i] = s[t] - v;
    if (t == 511) aux[blockIdx.x] = s[511];
}

__global__ __launch_bounds__(256) void scan_aux_kernel(int* aux, int nb) {
    __shared__ int s[256];
    int t = threadIdx.x;
    int v = (t < nb) ? aux[t] : 0;
    s[t] = v;
    __syncthreads();
    for (int off = 1; off < 256; off <<= 1) {
        int x = (t >= off) ? s[t - off] : 0;
        __syncthreads();
        s[t] += x;
        __syncthreads();
    }
    if (t < nb) aux[t] = s[t] - v;
}

__global__ void scan_add_kernel(int* rp, const int* __restrict__ aux, int N, int E) {
    int i = blockIdx.x * blockDim.x + threadIdx.x;
    if (i < N) rp[i] += aux[i >> 9];
    if (i == N) rp[N] = E;
}

__global__ void copy_int_kernel(const int* __restrict__ rp, int* fill, int n) {
    int i = blockIdx.x * blockDim.x + threadIdx.x;
    if (i < n) fill[i] = rp[i];
}

// --- bucketed edge sort (write-locality for fill + local histograms) ---

__global__ __launch_bounds__(256) void bkt_hist_kernel(const int* __restrict__ dst,
                                                       int* __restrict__ hcnt,
                                                       int E, int nbuk, int nblk) {
    __shared__ int lh[128];
    int t = threadIdx.x;
    for (int i = t; i < nbuk; i += 256) lh[i] = 0;
    __syncthreads();
    int base = blockIdx.x * EPB;
    int end = min(base + EPB, E);
    for (int e = base + t; e < end; e += 256)
        atomicAdd(&lh[dst[e] >> BUK_SHIFT], 1);
    __syncthreads();
    for (int i = t; i < nbuk; i += 256) hcnt[i * nblk + blockIdx.x] = lh[i];
}

__global__ __launch_bounds__(1024) void scan_flat_kernel(int* a, int n) {
    __shared__ int s[1024];
    int t = threadIdx.x;
    int per = (n + 1023) / 1024;
    int start = t * per, end = min(start + per, n);
    int sum = 0;
    for (int i = start; i < end; ++i) sum += a[i];
    s[t] = sum;
    __syncthreads();
    for (int off = 1; off < 1024; off <<= 1) {
        int x = (t >= off) ? s[t - off] : 0;
        __syncthreads();
        s[t] += x;
        __syncthreads();
    }
    int run = s[t] - sum;
    for (int i = start; i < end; ++i) { int v = a[i]; a[i] = run; run += v; }
}

__global__ __launch_bounds__(256) void bkt_scatter_kernel(const int* __restrict__ src,
                                                          const int* __restrict__ dst,
                                                          const int* __restrict__ obk,
                                                          unsigned long long* __restrict__ ebuf,
                                                          int E, int nbuk, int nblk) {
    __shared__ int cur[128];
    int t = threadIdx.x;
    for (int i = t; i < nbuk; i += 256) cur[i] = obk[i * nblk + blockIdx.x];
    __syncthreads();
    int base = blockIdx.x * EPB;
    int end = min(base + EPB, E);
    for (int e = base + t; e < end; e += 256) {
        int d = dst[e], s = src[e];
        int b = d >> BUK_SHIFT;
        int pos = atomicAdd(&cur[b], 1);
        ebuf[pos] = ((unsigned long long)(unsigned)d << 32) | (unsigned)s;
    }
}

// per-node degree from bucket-sorted records: one block per bucket, LDS-only
// atomics, coalesced final store. Fully writes cnt (no pre-zero needed).
__global__ __launch_bounds__(1024) void node_hist_kernel(const unsigned long long* __restrict__ ebuf,
                                                         const int* __restrict__ hcnt,
                                                         int* __restrict__ cnt,
                                                         int E, int N, int nbuk, int nblk) {
    __shared__ int lh[1024];
    const int b = blockIdx.x;
    const int t = threadIdx.x;
    lh[t] = 0;
    __syncthreads();
    const int st = hcnt[b * nblk];
    const int en = (b + 1 < nbuk) ? hcnt[(b + 1) * nblk] : E;
    for (int e = st + t; e < en; e += 1024) {
        int d = (int)(unsigned)(ebuf[e] >> 32);
        atomicAdd(&lh[d & 1023], 1);
    }
    __syncthreads();
    int node = (b << BUK_SHIFT) + t;
    if (node < N) cnt[node] = lh[t];
}

__global__ void fill_csr_kernel(const unsigned long long* __restrict__ ebuf,
                                int* fill, int* __restrict__ col, int E) {
    int e = blockIdx.x * blockDim.x + threadIdx.x;
    if (e >= E) return;
    unsigned long long r = ebuf[e];
    int s = (int)(unsigned)(r & 0xFFFFFFFFull);
    int d = (int)(unsigned)(r >> 32);
    int pos = atomicAdd(&fill[d], 1);
    col[pos] = s;
}

// ---------------- W prep: fp32 [K][F] -> split-bf16 in MFMA B-fragment order ----

template<int K, int F>
__global__ void wprep_kernel(const float* __restrict__ W, short* __restrict__ whi,
                             short* __restrict__ wlo) {
    constexpr int CB = F / 16;
    int idx = blockIdx.x * 256 + threadIdx.x;
    if (idx >= K * F) return;
    int e = idx & 7;
    int lane = (idx >> 3) & 63;
    int fc = idx >> 9;               // kb*CB + cb
    int kb = fc / CB, cb = fc % CB;
    int k = kb * 32 + (lane >> 4) * 8 + e;
    int colv = cb * 16 + (lane & 15);
    BF16Pair p = split_bf16(W[k * F + colv]);
    whi[idx] = p.hi;
    wlo[idx] = p.lo;
}

// ---------------- MFMA GEMM: H[N,F] = fp16( dinv[r] * (A[N,K] @ W[K,F]) ) --------
// B (hi+lo fragments) double-buffered in LDS, shared by 4 waves. Raw s_barrier +
// counted waits keep next-tile global loads in flight across the barrier.

template<int K, int F, typename AT>
__global__ __launch_bounds__(256) void mfma_gemm(const AT* __restrict__ A,
                                                 const short* __restrict__ Whi,
                                                 const short* __restrict__ Wlo,
                                                 const float* __restrict__ dinv,
                                                 _Float16* __restrict__ H, int N) {
    constexpr int CB = F / 16;
    constexpr int KB = K / 32;
    constexpr int MT = 2;                 // row-frags per wave
    constexpr int HCH = CB * 64;          // 16B chunks per (hi or lo) stream per kb
    constexpr int CHUNKS = HCH * 2;
    constexpr int CPT = CHUNKS / 256;

    __shared__ __align__(16) short Bs[2][CB * 1024];   // [buf][hi: CB*512 | lo: CB*512]

    const int tid = threadIdx.x;
    const int wid = tid >> 6, lane = tid & 63;
    const int rowf = lane & 15;
    const int kgrp = lane >> 4;
    const long long row0 = (long long)blockIdx.x * (MT * 16 * 4) + wid * (MT * 16);

    f32x4 acc[MT][CB] = {};
    short8 breg[CPT];
    float fvaC[MT][8], fvaN[MT][8];

    auto stage_issue = [&](int kb) {
#pragma unroll
        for (int i = 0; i < CPT; ++i) {
            int c = tid + i * 256;
            const short* p = (c < HCH) ? (Whi + (size_t)kb * (CB * 512) + (size_t)c * 8)
                                       : (Wlo + (size_t)kb * (CB * 512) + (size_t)(c - HCH) * 8);
            breg[i] = *(const short8*)p;
        }
    };
    auto stage_write = [&](int b) {
#pragma unroll
        for (int i = 0; i < CPT; ++i) {
            int c = tid + i * 256;
            *(short8*)&Bs[b][(size_t)c * 8] = breg[i];
        }
    };
    auto a_load = [&](float (&dst)[MT][8], int kb) {
#pragma unroll
        for (int mt = 0; mt < MT; ++mt) {
            long long r = row0 + mt * 16 + rowf;
            if (r < N) {
                const AT* ap = A + (size_t)r * K + kb * 32 + kgrp * 8;
                if constexpr (sizeof(AT) == 4) {
                    float4 f0 = ((const float4*)ap)[0];
                    float4 f1 = ((const float4*)ap)[1];
                    dst[mt][0]=f0.x; dst[mt][1]=f0.y; dst[mt][2]=f0.z; dst[mt][3]=f0.w;
                    dst[mt][4]=f1.x; dst[mt][5]=f1.y; dst[mt][6]=f1.z; dst[mt][7]=f1.w;
                } else {
                    h16x8 hv = *(const h16x8*)ap;
#pragma unroll
                    for (int j = 0; j < 8; ++j) dst[mt][j] = (float)hv[j];
                }
            } else {
#pragma unroll
                for (int j = 0; j < 8; ++j) dst[mt][j] = 0.f;
            }
        }
    };

    stage_issue(0);
    a_load(fvaC, 0);

    for (int kb = 0; kb < KB; ++kb) {
        const int b = kb & 1;
        stage_write(b);
        if (kb + 1 < KB) stage_issue(kb + 1);
        asm volatile("s_waitcnt lgkmcnt(0)" ::: "memory");
        __builtin_amdgcn_s_barrier();
        __builtin_amdgcn_sched_barrier(0);
        if (kb + 1 < KB) a_load(fvaN, kb + 1);

        short8 ahi[MT], alo[MT];
#pragma unroll
        for (int mt = 0; mt < MT; ++mt) {
#pragma unroll
            for (int j = 0; j < 8; ++j) {
                BF16Pair p = split_bf16(fvaC[mt][j]);
                ahi[mt][j] = p.hi;
                alo[mt][j] = p.lo;
            }
        }
#pragma unroll
        for (int cb = 0; cb < CB; ++cb) {
            short8 bhi = *(const short8*)&Bs[b][((size_t)cb * 64 + lane) * 8];
            short8 blo = *(const short8*)&Bs[b][CB * 512 + ((size_t)cb * 64 + lane) * 8];
#pragma unroll
            for (int mt = 0; mt < MT; ++mt) {
                acc[mt][cb] = __builtin_amdgcn_mfma_f32_16x16x32_bf16(ahi[mt], bhi, acc[mt][cb], 0, 0, 0);
                acc[mt][cb] = __builtin_amdgcn_mfma_f32_16x16x32_bf16(alo[mt], bhi, acc[mt][cb], 0, 0, 0);
                acc[mt][cb] = __builtin_amdgcn_mfma_f32_16x16x32_bf16(ahi[mt], blo, acc[mt][cb], 0, 0, 0);
            }
        }
#pragma unroll
        for (int mt = 0; mt < MT; ++mt)
#pragma unroll
            for (int j = 0; j < 8; ++j) fvaC[mt][j] = fvaN[mt][j];
    }

    const int rsub = (lane >> 4) * 4;
#pragma unroll
    for (int mt = 0; mt < MT; ++mt) {
        long long rbase = row0 + mt * 16 + rsub;
        float dv[4];
#pragma unroll
        for (int j = 0; j < 4; ++j) dv[j] = (rbase + j < N) ? dinv[rbase + j] : 0.f;
#pragma unroll
        for (int cb = 0; cb < CB; ++cb) {
            int colv = cb * 16 + rowf;
#pragma unroll
            for (int j = 0; j < 4; ++j) {
                long long r = rbase + j;
                if (r < N) H[(size_t)r * F + colv] = (_Float16)(acc[mt][cb][j] * dv[j]);
            }
        }
    }
}

// ---------------- fused CSR aggregation (fp16 gather, fp32 accum) ----------------

template<int F, bool RELU, typename OutT>
__global__ __launch_bounds__(256) void agg_kernel(const _Float16* __restrict__ hs,
                                                  const int* __restrict__ rp,
                                                  const int* __restrict__ col,
                                                  const float* __restrict__ dinv,
                                                  const float* __restrict__ bias,
                                                  OutT* __restrict__ out, int N) {
    constexpr int LPN = F / 8;            // lanes per node, 16B/lane
    constexpr int NPB = 256 / LPN;
    const int tid = threadIdx.x;
    const int lane = tid % LPN;
    const int node = blockIdx.x * NPB + tid / LPN;
    if (node >= N) return;

    const int f0 = lane * 8;
    const _Float16* hbase = hs + f0;

    float acc[8];
    {
        h16x8 sv = *(const h16x8*)(hbase + (size_t)node * F);
#pragma unroll
        for (int v = 0; v < 8; ++v) acc[v] = (float)sv[v];
    }

    int e = rp[node];
    const int e1 = rp[node + 1];
    for (; e + 4 <= e1; e += 4) {
        int s0 = col[e], s1 = col[e + 1], s2 = col[e + 2], s3 = col[e + 3];
        h16x8 v0 = *(const h16x8*)(hbase + (size_t)s0 * F);
        h16x8 v1 = *(const h16x8*)(hbase + (size_t)s1 * F);
        h16x8 v2 = *(const h16x8*)(hbase + (size_t)s2 * F);
        h16x8 v3 = *(const h16x8*)(hbase + (size_t)s3 * F);
#pragma unroll
        for (int v = 0; v < 8; ++v)
            acc[v] += ((float)v0[v] + (float)v1[v]) + ((float)v2[v] + (float)v3[v]);
    }
    for (; e < e1; ++e) {
        h16x8 v0 = *(const h16x8*)(hbase + (size_t)col[e] * F);
#pragma unroll
        for (int v = 0; v < 8; ++v) acc[v] += (float)v0[v];
    }

    const float self = dinv[node];
    OutT* op = out + (size_t)node * F + f0;
    const float* bp = bias + f0;
#pragma unroll
    for (int v = 0; v < 8; ++v) {
        float r = fmaf(acc[v], self, bp[v]);
        if (RELU) r = fmaxf(r, 0.f);
        op[v] = (OutT)r;
    }
}

// ---------------- launcher ----------------

extern "C" void kernel_launch(void* const* d_in, const int* in_sizes, int n_in,
                              void* d_out, int out_size, void* d_ws, size_t ws_size,
                              hipStream_t stream) {
    const float* x  = (const float*)d_in[0];
    const int*   ei = (const int*)d_in[1];
    const float* W1 = (const float*)d_in[2];
    const float* b1 = (const float*)d_in[3];
    const float* W2 = (const float*)d_in[4];
    const float* b2 = (const float*)d_in[5];
    const float* W3 = (const float*)d_in[6];
    const float* b3 = (const float*)d_in[7];
    const float* W4 = (const float*)d_in[8];
    const float* b4 = (const float*)d_in[9];

    const int N = in_sizes[0] / 256;
    const int E = in_sizes[1] / 2;
    const int* src = ei;
    const int* dst = ei + E;

    const int NB   = CDIV(N, 512);
    const int nbuk = ((N - 1) >> BUK_SHIFT) + 1;
    const int nblk = CDIV(E, EPB);

    char* base = (char*)d_ws;
    size_t o = 0;
    auto alloc = [&](size_t bytes) { char* p = base + o; o += (bytes + 255) & ~(size_t)255; return p; };
    int*   cnt  = (int*)  alloc(sizeof(int) * N);        // degree, then bucket cursor
    int*   rp   = (int*)  alloc(sizeof(int) * (N + 1));
    int*   aux  = (int*)  alloc(sizeof(int) * 256);
    float* dinv = (float*)alloc(sizeof(float) * N);
    int*   col  = (int*)  alloc(sizeof(int) * E);
    int*   hcnt = (int*)  alloc(sizeof(int) * (size_t)nbuk * nblk);
    unsigned long long* ebuf = (unsigned long long*)alloc(sizeof(unsigned long long) * E);
    short* w1h  = (short*)alloc(sizeof(short) * 256 * 128);
    short* w1l  = (short*)alloc(sizeof(short) * 256 * 128);
    short* w2h  = (short*)alloc(sizeof(short) * 128 * 128);
    short* w2l  = (short*)alloc(sizeof(short) * 128 * 128);
    short* w3h  = (short*)alloc(sizeof(short) * 128 * 64);
    short* w3l  = (short*)alloc(sizeof(short) * 128 * 64);
    short* w4h  = (short*)alloc(sizeof(short) * 64 * 32);
    short* w4l  = (short*)alloc(sizeof(short) * 64 * 32);
    _Float16* hsbuf = (_Float16*)alloc(sizeof(_Float16) * (size_t)N * 128);
    _Float16* zsbuf = (_Float16*)alloc(sizeof(_Float16) * (size_t)N * 128);
    float* out  = (float*)d_out;

    // --- weight prep (split-bf16, fragment-swizzled) ---
    wprep_kernel<256, 128><<<CDIV(256 * 128, 256), 256, 0, stream>>>(W1, w1h, w1l);
    wprep_kernel<128, 128><<<CDIV(128 * 128, 256), 256, 0, stream>>>(W2, w2h, w2l);
    wprep_kernel<128, 64><<<CDIV(128 * 64, 256), 256, 0, stream>>>(W3, w3h, w3l);
    wprep_kernel<64, 32><<<CDIV(64 * 32, 256), 256, 0, stream>>>(W4, w4h, w4l);

    // --- bucketed edge sort ---
    bkt_hist_kernel<<<nblk, 256, 0, stream>>>(dst, hcnt, E, nbuk, nblk);
    scan_flat_kernel<<<1, 1024, 0, stream>>>(hcnt, nbuk * nblk);
    bkt_scatter_kernel<<<nblk, 256, 0, stream>>>(src, dst, hcnt, ebuf, E, nbuk, nblk);

    // --- per-node degree from sorted records (LDS-only atomics) ---
    node_hist_kernel<<<nbuk, 1024, 0, stream>>>(ebuf, hcnt, cnt, E, N, nbuk, nblk);
    dinv_kernel<<<CDIV(N, 256), 256, 0, stream>>>(cnt, dinv, N);
    scan_block_kernel<<<NB, 512, 0, stream>>>(cnt, rp, aux, N);
    scan_aux_kernel<<<1, 256, 0, stream>>>(aux, NB);
    scan_add_kernel<<<CDIV(N + 1, 256), 256, 0, stream>>>(rp, aux, N, E);
    copy_int_kernel<<<CDIV(N, 256), 256, 0, stream>>>(rp, cnt, N);
    fill_csr_kernel<<<CDIV(E, 256), 256, 0, stream>>>(ebuf, cnt, col, E);

    const int GG = CDIV(N, 128);  // gemm grid (128 rows/block)

    // --- layer 1 ---
    mfma_gemm<256, 128, float><<<GG, 256, 0, stream>>>(x, w1h, w1l, dinv, hsbuf, N);
    agg_kernel<128, true, _Float16><<<CDIV(N, 16), 256, 0, stream>>>(hsbuf, rp, col, dinv, b1, zsbuf, N);

    // --- layer 2 ---
    mfma_gemm<128, 128, _Float16><<<GG, 256, 0, stream>>>(zsbuf, w2h, w2l, dinv, hsbuf, N);
    agg_kernel<128, true, _Float16><<<CDIV(N, 16), 256, 0, stream>>>(hsbuf, rp, col, dinv, b2, zsbuf, N);

    // --- layer 3 ---
    mfma_gemm<128, 64, _Float16><<<GG, 256, 0, stream>>>(zsbuf, w3h, w3l, dinv, hsbuf, N);
    agg_kernel<64, true, _Float16><<<CDIV(N, 32), 256, 0, stream>>>(hsbuf, rp, col, dinv, b3, zsbuf, N);

    // --- layer 4 ---
    mfma_gemm<64, 32, _Float16><<<GG, 256, 0, stream>>>(zsbuf, w4h, w4l, dinv, hsbuf, N);
    agg_kernel<32, false, float><<<CDIV(N, 64), 256, 0, stream>>>(hsbuf, rp, col, dinv, b4, out, N);
}

// Round 12
// 411.875 us; speedup vs baseline: 1.4019x; 1.0028x over previous
//
#include <hip/hip_runtime.h>

#define CDIV(a,b) (((a)+(b)-1)/(b))
#define BUK_SHIFT 10
#define EPB 4096   // edges per bucketize block

typedef float f32x4 __attribute__((ext_vector_type(4)));
typedef short short8 __attribute__((ext_vector_type(8)));
typedef _Float16 h16x8 __attribute__((ext_vector_type(8)));

// ---------------- bf16 helpers (RNE) ----------------

__device__ inline unsigned short rne_bf16(float f) {
    unsigned int u = __builtin_bit_cast(unsigned int, f);
    u += 0x7FFFu + ((u >> 16) & 1u);
    return (unsigned short)(u >> 16);
}

struct BF16Pair { short hi, lo; };

__device__ inline BF16Pair split_bf16(float f) {
    unsigned short h = rne_bf16(f);
    float fh = __builtin_bit_cast(float, (unsigned int)h << 16);
    BF16Pair p;
    p.hi = (short)h;
    p.lo = (short)rne_bf16(f - fh);
    return p;
}

// ---------------- CSR build ----------------

__global__ void dinv_kernel(const int* __restrict__ cnt, float* dinv, int n) {
    int i = blockIdx.x * blockDim.x + threadIdx.x;
    if (i < n) dinv[i] = rsqrtf((float)cnt[i] + 1.0f);
}

__global__ __launch_bounds__(512) void scan_block_kernel(const int* __restrict__ cnt,
                                                         int* rp, int* aux, int N) {
    __shared__ int s[512];
    int t = threadIdx.x;
    int i = blockIdx.x * 512 + t;
    int v = (i < N) ? cnt[i] : 0;
    s[t] = v;
    __syncthreads();
    for (int off = 1; off < 512; off <<= 1) {
        int x = (t >= off) ? s[t - off] : 0;
        __syncthreads();
        s[t] += x;
        __syncthreads();
    }
    if (i < N) rp[i] = s[t] - v;
    if (t == 511) aux[blockIdx.x] = s[511];
}

__global__ __launch_bounds__(256) void scan_aux_kernel(int* aux, int nb) {
    __shared__ int s[256];
    int t = threadIdx.x;
    int v = (t < nb) ? aux[t] : 0;
    s[t] = v;
    __syncthreads();
    for (int off = 1; off < 256; off <<= 1) {
        int x = (t >= off) ? s[t - off] : 0;
        __syncthreads();
        s[t] += x;
        __syncthreads();
    }
    if (t < nb) aux[t] = s[t] - v;
}

__global__ void scan_add_kernel(int* rp, const int* __restrict__ aux, int N, int E) {
    int i = blockIdx.x * blockDim.x + threadIdx.x;
    if (i < N) rp[i] += aux[i >> 9];
    if (i == N) rp[N] = E;
}

__global__ void copy_int_kernel(const int* __restrict__ rp, int* fill, int n) {
    int i = blockIdx.x * blockDim.x + threadIdx.x;
    if (i < n) fill[i] = rp[i];
}

// --- bucketed edge sort (write-locality for fill + local histograms) ---

__global__ __launch_bounds__(256) void bkt_hist_kernel(const int* __restrict__ dst,
                                                       int* __restrict__ hcnt,
                                                       int E, int nbuk, int nblk) {
    __shared__ int lh[128];
    int t = threadIdx.x;
    for (int i = t; i < nbuk; i += 256) lh[i] = 0;
    __syncthreads();
    int base = blockIdx.x * EPB;
    int end = min(base + EPB, E);
    for (int e = base + t; e < end; e += 256)
        atomicAdd(&lh[dst[e] >> BUK_SHIFT], 1);
    __syncthreads();
    for (int i = t; i < nbuk; i += 256) hcnt[i * nblk + blockIdx.x] = lh[i];
}

__global__ __launch_bounds__(1024) void scan_flat_kernel(int* a, int n) {
    __shared__ int s[1024];
    int t = threadIdx.x;
    int per = (n + 1023) / 1024;
    int start = t * per, end = min(start + per, n);
    int sum = 0;
    for (int i = start; i < end; ++i) sum += a[i];
    s[t] = sum;
    __syncthreads();
    for (int off = 1; off < 1024; off <<= 1) {
        int x = (t >= off) ? s[t - off] : 0;
        __syncthreads();
        s[t] += x;
        __syncthreads();
    }
    int run = s[t] - sum;
    for (int i = start; i < end; ++i) { int v = a[i]; a[i] = run; run += v; }
}

__global__ __launch_bounds__(256) void bkt_scatter_kernel(const int* __restrict__ src,
                                                          const int* __restrict__ dst,
                                                          const int* __restrict__ obk,
                                                          unsigned long long* __restrict__ ebuf,
                                                          int E, int nbuk, int nblk) {
    __shared__ int cur[128];
    int t = threadIdx.x;
    for (int i = t; i < nbuk; i += 256) cur[i] = obk[i * nblk + blockIdx.x];
    __syncthreads();
    int base = blockIdx.x * EPB;
    int end = min(base + EPB, E);
    for (int e = base + t; e < end; e += 256) {
        int d = dst[e], s = src[e];
        int b = d >> BUK_SHIFT;
        int pos = atomicAdd(&cur[b], 1);
        ebuf[pos] = ((unsigned long long)(unsigned)d << 32) | (unsigned)s;
    }
}

// per-node degree from bucket-sorted records: one block per bucket, LDS-only
// atomics, coalesced final store. Fully writes cnt (no pre-zero needed).
__global__ __launch_bounds__(1024) void node_hist_kernel(const unsigned long long* __restrict__ ebuf,
                                                         const int* __restrict__ hcnt,
                                                         int* __restrict__ cnt,
                                                         int E, int N, int nbuk, int nblk) {
    __shared__ int lh[1024];
    const int b = blockIdx.x;
    const int t = threadIdx.x;
    lh[t] = 0;
    __syncthreads();
    const int st = hcnt[b * nblk];
    const int en = (b + 1 < nbuk) ? hcnt[(b + 1) * nblk] : E;
    for (int e = st + t; e < en; e += 1024) {
        int d = (int)(unsigned)(ebuf[e] >> 32);
        atomicAdd(&lh[d & 1023], 1);
    }
    __syncthreads();
    int node = (b << BUK_SHIFT) + t;
    if (node < N) cnt[node] = lh[t];
}

__global__ void fill_csr_kernel(const unsigned long long* __restrict__ ebuf,
                                int* fill, int* __restrict__ col, int E) {
    int e = blockIdx.x * blockDim.x + threadIdx.x;
    if (e >= E) return;
    unsigned long long r = ebuf[e];
    int s = (int)(unsigned)(r & 0xFFFFFFFFull);
    int d = (int)(unsigned)(r >> 32);
    int pos = atomicAdd(&fill[d], 1);
    col[pos] = s;
}

// ---------------- W prep: fp32 [K][F] -> split-bf16 in MFMA B-fragment order ----

template<int K, int F>
__global__ void wprep_kernel(const float* __restrict__ W, short* __restrict__ whi,
                             short* __restrict__ wlo) {
    constexpr int CB = F / 16;
    int idx = blockIdx.x * 256 + threadIdx.x;
    if (idx >= K * F) return;
    int e = idx & 7;
    int lane = (idx >> 3) & 63;
    int fc = idx >> 9;               // kb*CB + cb
    int kb = fc / CB, cb = fc % CB;
    int k = kb * 32 + (lane >> 4) * 8 + e;
    int colv = cb * 16 + (lane & 15);
    BF16Pair p = split_bf16(W[k * F + colv]);
    whi[idx] = p.hi;
    wlo[idx] = p.lo;
}

// ---------------- MFMA GEMM: H[N,F] = fp16( dinv[r] * (A[N,K] @ W[K,F]) ) --------
// MT=1: 16 rows/wave, 64 rows/block -> 2x grid for occupancy. B double-buffered
// in LDS; raw s_barrier + counted waits keep prefetch loads in flight.

template<int K, int F, typename AT>
__global__ __launch_bounds__(256) void mfma_gemm(const AT* __restrict__ A,
                                                 const short* __restrict__ Whi,
                                                 const short* __restrict__ Wlo,
                                                 const float* __restrict__ dinv,
                                                 _Float16* __restrict__ H, int N) {
    constexpr int CB = F / 16;
    constexpr int KB = K / 32;
    constexpr int HCH = CB * 64;          // 16B chunks per (hi or lo) stream per kb
    constexpr int CHUNKS = HCH * 2;
    constexpr int CPT = (CHUNKS + 255) / 256;

    __shared__ __align__(16) short Bs[2][CB * 1024];   // [buf][hi: CB*512 | lo: CB*512]

    const int tid = threadIdx.x;
    const int wid = tid >> 6, lane = tid & 63;
    const int rowf = lane & 15;
    const int kgrp = lane >> 4;
    const long long row0 = (long long)blockIdx.x * 64 + wid * 16;

    f32x4 acc[CB] = {};
    short8 breg[CPT];
    float fvaC[8], fvaN[8];

    auto stage_issue = [&](int kb) {
#pragma unroll
        for (int i = 0; i < CPT; ++i) {
            int c = tid + i * 256;
            if (CHUNKS < 256 && c >= CHUNKS) continue;
            const short* p = (c < HCH) ? (Whi + (size_t)kb * (CB * 512) + (size_t)c * 8)
                                       : (Wlo + (size_t)kb * (CB * 512) + (size_t)(c - HCH) * 8);
            breg[i] = *(const short8*)p;
        }
    };
    auto stage_write = [&](int b) {
#pragma unroll
        for (int i = 0; i < CPT; ++i) {
            int c = tid + i * 256;
            if (CHUNKS < 256 && c >= CHUNKS) continue;
            *(short8*)&Bs[b][(size_t)c * 8] = breg[i];
        }
    };
    auto a_load = [&](float (&dst)[8], int kb) {
        long long r = row0 + rowf;
        if (r < N) {
            const AT* ap = A + (size_t)r * K + kb * 32 + kgrp * 8;
            if constexpr (sizeof(AT) == 4) {
                float4 f0 = ((const float4*)ap)[0];
                float4 f1 = ((const float4*)ap)[1];
                dst[0]=f0.x; dst[1]=f0.y; dst[2]=f0.z; dst[3]=f0.w;
                dst[4]=f1.x; dst[5]=f1.y; dst[6]=f1.z; dst[7]=f1.w;
            } else {
                h16x8 hv = *(const h16x8*)ap;
#pragma unroll
                for (int j = 0; j < 8; ++j) dst[j] = (float)hv[j];
            }
        } else {
#pragma unroll
            for (int j = 0; j < 8; ++j) dst[j] = 0.f;
        }
    };

    stage_issue(0);
    a_load(fvaC, 0);

    for (int kb = 0; kb < KB; ++kb) {
        const int b = kb & 1;
        stage_write(b);
        if (kb + 1 < KB) stage_issue(kb + 1);
        asm volatile("s_waitcnt lgkmcnt(0)" ::: "memory");
        __builtin_amdgcn_s_barrier();
        __builtin_amdgcn_sched_barrier(0);
        if (kb + 1 < KB) a_load(fvaN, kb + 1);

        short8 ahi, alo;
#pragma unroll
        for (int j = 0; j < 8; ++j) {
            BF16Pair p = split_bf16(fvaC[j]);
            ahi[j] = p.hi;
            alo[j] = p.lo;
        }
#pragma unroll
        for (int cb = 0; cb < CB; ++cb) {
            short8 bhi = *(const short8*)&Bs[b][((size_t)cb * 64 + lane) * 8];
            short8 blo = *(const short8*)&Bs[b][CB * 512 + ((size_t)cb * 64 + lane) * 8];
            acc[cb] = __builtin_amdgcn_mfma_f32_16x16x32_bf16(ahi, bhi, acc[cb], 0, 0, 0);
            acc[cb] = __builtin_amdgcn_mfma_f32_16x16x32_bf16(alo, bhi, acc[cb], 0, 0, 0);
            acc[cb] = __builtin_amdgcn_mfma_f32_16x16x32_bf16(ahi, blo, acc[cb], 0, 0, 0);
        }
#pragma unroll
        for (int j = 0; j < 8; ++j) fvaC[j] = fvaN[j];
    }

    // D layout: col = lane&15, row = (lane>>4)*4 + j ; scale by dinv[row], cvt fp16
    const int rsub = (lane >> 4) * 4;
    long long rbase = row0 + rsub;
    float dv[4];
#pragma unroll
    for (int j = 0; j < 4; ++j) dv[j] = (rbase + j < N) ? dinv[rbase + j] : 0.f;
#pragma unroll
    for (int cb = 0; cb < CB; ++cb) {
        int colv = cb * 16 + rowf;
#pragma unroll
        for (int j = 0; j < 4; ++j) {
            long long r = rbase + j;
            if (r < N) H[(size_t)r * F + colv] = (_Float16)(acc[cb][j] * dv[j]);
        }
    }
}

// ---------------- fused CSR aggregation (fp16 gather, fp32 accum) ----------------

template<int F, bool RELU, typename OutT>
__global__ __launch_bounds__(256) void agg_kernel(const _Float16* __restrict__ hs,
                                                  const int* __restrict__ rp,
                                                  const int* __restrict__ col,
                                                  const float* __restrict__ dinv,
                                                  const float* __restrict__ bias,
                                                  OutT* __restrict__ out, int N) {
    constexpr int LPN = F / 8;            // lanes per node, 16B/lane
    constexpr int NPB = 256 / LPN;
    const int tid = threadIdx.x;
    const int lane = tid % LPN;
    const int node = blockIdx.x * NPB + tid / LPN;
    if (node >= N) return;

    const int f0 = lane * 8;
    const _Float16* hbase = hs + f0;

    float acc[8];
    {
        h16x8 sv = *(const h16x8*)(hbase + (size_t)node * F);
#pragma unroll
        for (int v = 0; v < 8; ++v) acc[v] = (float)sv[v];
    }

    int e = rp[node];
    const int e1 = rp[node + 1];
    for (; e + 4 <= e1; e += 4) {
        int s0 = col[e], s1 = col[e + 1], s2 = col[e + 2], s3 = col[e + 3];
        h16x8 v0 = *(const h16x8*)(hbase + (size_t)s0 * F);
        h16x8 v1 = *(const h16x8*)(hbase + (size_t)s1 * F);
        h16x8 v2 = *(const h16x8*)(hbase + (size_t)s2 * F);
        h16x8 v3 = *(const h16x8*)(hbase + (size_t)s3 * F);
#pragma unroll
        for (int v = 0; v < 8; ++v)
            acc[v] += ((float)v0[v] + (float)v1[v]) + ((float)v2[v] + (float)v3[v]);
    }
    for (; e < e1; ++e) {
        h16x8 v0 = *(const h16x8*)(hbase + (size_t)col[e] * F);
#pragma unroll
        for (int v = 0; v < 8; ++v) acc[v] += (float)v0[v];
    }

    const float self = dinv[node];
    OutT* op = out + (size_t)node * F + f0;
    const float* bp = bias + f0;
#pragma unroll
    for (int v = 0; v < 8; ++v) {
        float r = fmaf(acc[v], self, bp[v]);
        if (RELU) r = fmaxf(r, 0.f);
        op[v] = (OutT)r;
    }
}

// ---------------- launcher ----------------

extern "C" void kernel_launch(void* const* d_in, const int* in_sizes, int n_in,
                              void* d_out, int out_size, void* d_ws, size_t ws_size,
                              hipStream_t stream) {
    const float* x  = (const float*)d_in[0];
    const int*   ei = (const int*)d_in[1];
    const float* W1 = (const float*)d_in[2];
    const float* b1 = (const float*)d_in[3];
    const float* W2 = (const float*)d_in[4];
    const float* b2 = (const float*)d_in[5];
    const float* W3 = (const float*)d_in[6];
    const float* b3 = (const float*)d_in[7];
    const float* W4 = (const float*)d_in[8];
    const float* b4 = (const float*)d_in[9];

    const int N = in_sizes[0] / 256;
    const int E = in_sizes[1] / 2;
    const int* src = ei;
    const int* dst = ei + E;

    const int NB   = CDIV(N, 512);
    const int nbuk = ((N - 1) >> BUK_SHIFT) + 1;
    const int nblk = CDIV(E, EPB);

    char* base = (char*)d_ws;
    size_t o = 0;
    auto alloc = [&](size_t bytes) { char* p = base + o; o += (bytes + 255) & ~(size_t)255; return p; };
    int*   cnt  = (int*)  alloc(sizeof(int) * N);        // degree, then bucket cursor
    int*   rp   = (int*)  alloc(sizeof(int) * (N + 1));
    int*   aux  = (int*)  alloc(sizeof(int) * 256);
    float* dinv = (float*)alloc(sizeof(float) * N);
    int*   col  = (int*)  alloc(sizeof(int) * E);
    int*   hcnt = (int*)  alloc(sizeof(int) * (size_t)nbuk * nblk);
    unsigned long long* ebuf = (unsigned long long*)alloc(sizeof(unsigned long long) * E);
    short* w1h  = (short*)alloc(sizeof(short) * 256 * 128);
    short* w1l  = (short*)alloc(sizeof(short) * 256 * 128);
    short* w2h  = (short*)alloc(sizeof(short) * 128 * 128);
    short* w2l  = (short*)alloc(sizeof(short) * 128 * 128);
    short* w3h  = (short*)alloc(sizeof(short) * 128 * 64);
    short* w3l  = (short*)alloc(sizeof(short) * 128 * 64);
    short* w4h  = (short*)alloc(sizeof(short) * 64 * 32);
    short* w4l  = (short*)alloc(sizeof(short) * 64 * 32);
    _Float16* hsbuf = (_Float16*)alloc(sizeof(_Float16) * (size_t)N * 128);
    _Float16* zsbuf = (_Float16*)alloc(sizeof(_Float16) * (size_t)N * 128);
    float* out  = (float*)d_out;

    // --- weight prep (split-bf16, fragment-swizzled) ---
    wprep_kernel<256, 128><<<CDIV(256 * 128, 256), 256, 0, stream>>>(W1, w1h, w1l);
    wprep_kernel<128, 128><<<CDIV(128 * 128, 256), 256, 0, stream>>>(W2, w2h, w2l);
    wprep_kernel<128, 64><<<CDIV(128 * 64, 256), 256, 0, stream>>>(W3, w3h, w3l);
    wprep_kernel<64, 32><<<CDIV(64 * 32, 256), 256, 0, stream>>>(W4, w4h, w4l);

    // --- bucketed edge sort ---
    bkt_hist_kernel<<<nblk, 256, 0, stream>>>(dst, hcnt, E, nbuk, nblk);
    scan_flat_kernel<<<1, 1024, 0, stream>>>(hcnt, nbuk * nblk);
    bkt_scatter_kernel<<<nblk, 256, 0, stream>>>(src, dst, hcnt, ebuf, E, nbuk, nblk);

    // --- per-node degree from sorted records (LDS-only atomics) ---
    node_hist_kernel<<<nbuk, 1024, 0, stream>>>(ebuf, hcnt, cnt, E, N, nbuk, nblk);
    dinv_kernel<<<CDIV(N, 256), 256, 0, stream>>>(cnt, dinv, N);
    scan_block_kernel<<<NB, 512, 0, stream>>>(cnt, rp, aux, N);
    scan_aux_kernel<<<1, 256, 0, stream>>>(aux, NB);
    scan_add_kernel<<<CDIV(N + 1, 256), 256, 0, stream>>>(rp, aux, N, E);
    copy_int_kernel<<<CDIV(N, 256), 256, 0, stream>>>(rp, cnt, N);
    fill_csr_kernel<<<CDIV(E, 256), 256, 0, stream>>>(ebuf, cnt, col, E);

    const int GG = CDIV(N, 64);  // gemm grid (64 rows/block)

    // --- layer 1 ---
    mfma_gemm<256, 128, float><<<GG, 256, 0, stream>>>(x, w1h, w1l, dinv, hsbuf, N);
    agg_kernel<128, true, _Float16><<<CDIV(N, 16), 256, 0, stream>>>(hsbuf, rp, col, dinv, b1, zsbuf, N);

    // --- layer 2 ---
    mfma_gemm<128, 128, _Float16><<<GG, 256, 0, stream>>>(zsbuf, w2h, w2l, dinv, hsbuf, N);
    agg_kernel<128, true, _Float16><<<CDIV(N, 16), 256, 0, stream>>>(hsbuf, rp, col, dinv, b2, zsbuf, N);

    // --- layer 3 ---
    mfma_gemm<128, 64, _Float16><<<GG, 256, 0, stream>>>(zsbuf, w3h, w3l, dinv, hsbuf, N);
    agg_kernel<64, true, _Float16><<<CDIV(N, 32), 256, 0, stream>>>(hsbuf, rp, col, dinv, b3, zsbuf, N);

    // --- layer 4 ---
    mfma_gemm<64, 32, _Float16><<<GG, 256, 0, stream>>>(zsbuf, w4h, w4l, dinv, hsbuf, N);
    agg_kernel<32, false, float><<<CDIV(N, 64), 256, 0, stream>>>(hsbuf, rp, col, dinv, b4, out, N);
}

// Round 13
// 367.212 us; speedup vs baseline: 1.5724x; 1.1216x over previous
//
#include <hip/hip_runtime.h>

#define CDIV(a,b) (((a)+(b)-1)/(b))
#define BUK_SHIFT 10
#define EPB 4096   // edges per bucketize block

typedef float f32x4 __attribute__((ext_vector_type(4)));
typedef short short8 __attribute__((ext_vector_type(8)));
typedef _Float16 h16x8 __attribute__((ext_vector_type(8)));

// ---------------- bf16 helpers (RNE) ----------------

__device__ inline unsigned short rne_bf16(float f) {
    unsigned int u = __builtin_bit_cast(unsigned int, f);
    u += 0x7FFFu + ((u >> 16) & 1u);
    return (unsigned short)(u >> 16);
}

struct BF16Pair { short hi, lo; };

__device__ inline BF16Pair split_bf16(float f) {
    unsigned short h = rne_bf16(f);
    float fh = __builtin_bit_cast(float, (unsigned int)h << 16);
    BF16Pair p;
    p.hi = (short)h;
    p.lo = (short)rne_bf16(f - fh);
    return p;
}

// ---------------- bucketed edge sort ----------------

__global__ __launch_bounds__(256) void bkt_hist_kernel(const int* __restrict__ dst,
                                                       int* __restrict__ hcnt,
                                                       int E, int nbuk, int nblk) {
    __shared__ int lh[128];
    int t = threadIdx.x;
    for (int i = t; i < nbuk; i += 256) lh[i] = 0;
    __syncthreads();
    int base = blockIdx.x * EPB;
    int end = min(base + EPB, E);
    for (int e = base + t; e < end; e += 256)
        atomicAdd(&lh[dst[e] >> BUK_SHIFT], 1);
    __syncthreads();
    for (int i = t; i < nbuk; i += 256) hcnt[i * nblk + blockIdx.x] = lh[i];
}

__global__ __launch_bounds__(1024) void scan_flat_kernel(int* a, int n) {
    __shared__ int s[1024];
    int t = threadIdx.x;
    int per = (n + 1023) / 1024;
    int start = t * per, end = min(start + per, n);
    int sum = 0;
    for (int i = start; i < end; ++i) sum += a[i];
    s[t] = sum;
    __syncthreads();
    for (int off = 1; off < 1024; off <<= 1) {
        int x = (t >= off) ? s[t - off] : 0;
        __syncthreads();
        s[t] += x;
        __syncthreads();
    }
    int run = s[t] - sum;
    for (int i = start; i < end; ++i) { int v = a[i]; a[i] = run; run += v; }
}

__global__ __launch_bounds__(256) void bkt_scatter_kernel(const int* __restrict__ src,
                                                          const int* __restrict__ dst,
                                                          const int* __restrict__ obk,
                                                          unsigned long long* __restrict__ ebuf,
                                                          int E, int nbuk, int nblk) {
    __shared__ int cur[128];
    int t = threadIdx.x;
    for (int i = t; i < nbuk; i += 256) cur[i] = obk[i * nblk + blockIdx.x];
    __syncthreads();
    int base = blockIdx.x * EPB;
    int end = min(base + EPB, E);
    for (int e = base + t; e < end; e += 256) {
        int d = dst[e], s = src[e];
        int b = d >> BUK_SHIFT;
        int pos = atomicAdd(&cur[b], 1);
        ebuf[pos] = ((unsigned long long)(unsigned)d << 32) | (unsigned)s;
    }
}

// ---------------- fused per-bucket CSR build ----------------
// One block per bucket b (1024 nodes). Bucket records = ebuf[st,en);
// col region for the bucket is the SAME window [st,en) since rp = scan(deg).
// Does: LDS hist -> LDS exclusive scan -> rp/dinv (coalesced stores)
// -> LDS-cursor fill of col. Zero global atomics.
__global__ __launch_bounds__(1024) void bucket_csr_kernel(const unsigned long long* __restrict__ ebuf,
                                                          const int* __restrict__ hcnt,
                                                          int* __restrict__ rp,
                                                          float* __restrict__ dinv,
                                                          int* __restrict__ col,
                                                          int E, int N, int nbuk, int nblk) {
    __shared__ int lh[1024];
    __shared__ int lsc[1024];
    const int b = blockIdx.x;
    const int t = threadIdx.x;
    lh[t] = 0;
    __syncthreads();
    const int st = hcnt[b * nblk];
    const int en = (b + 1 < nbuk) ? hcnt[(b + 1) * nblk] : E;
    for (int e = st + t; e < en; e += 1024)
        atomicAdd(&lh[((int)(unsigned)(ebuf[e] >> 32)) & 1023], 1);
    __syncthreads();
    const int deg = lh[t];
    lsc[t] = deg;
    __syncthreads();
    for (int off = 1; off < 1024; off <<= 1) {
        int x = (t >= off) ? lsc[t - off] : 0;
        __syncthreads();
        lsc[t] += x;
        __syncthreads();
    }
    const int excl = lsc[t] - deg;           // bucket-local exclusive scan
    const int node = (b << BUK_SHIFT) + t;
    if (node < N) {
        rp[node] = st + excl;
        dinv[node] = rsqrtf((float)deg + 1.0f);
    }
    if (b == 0 && t == 0) rp[N] = E;
    __syncthreads();
    lh[t] = st + excl;                        // reuse lh as fill cursors
    __syncthreads();
    for (int e = st + t; e < en; e += 1024) {
        unsigned long long r = ebuf[e];
        int d = (int)(unsigned)(r >> 32);
        int pos = atomicAdd(&lh[d & 1023], 1);
        col[pos] = (int)(unsigned)(r & 0xFFFFFFFFull);
    }
}

// ---------------- W prep: fp32 [K][F] -> split-bf16 in MFMA B-fragment order ----

template<int K, int F>
__global__ void wprep_kernel(const float* __restrict__ W, short* __restrict__ whi,
                             short* __restrict__ wlo) {
    constexpr int CB = F / 16;
    int idx = blockIdx.x * 256 + threadIdx.x;
    if (idx >= K * F) return;
    int e = idx & 7;
    int lane = (idx >> 3) & 63;
    int fc = idx >> 9;               // kb*CB + cb
    int kb = fc / CB, cb = fc % CB;
    int k = kb * 32 + (lane >> 4) * 8 + e;
    int colv = cb * 16 + (lane & 15);
    BF16Pair p = split_bf16(W[k * F + colv]);
    whi[idx] = p.hi;
    wlo[idx] = p.lo;
}

// ---------------- MFMA GEMM: H[N,F] = fp16( dinv[r] * (A[N,K] @ W[K,F]) ) --------
// MT=1: 16 rows/wave, 64 rows/block. B double-buffered in LDS; raw s_barrier +
// counted waits keep prefetch loads in flight across the barrier.

template<int K, int F, typename AT>
__global__ __launch_bounds__(256) void mfma_gemm(const AT* __restrict__ A,
                                                 const short* __restrict__ Whi,
                                                 const short* __restrict__ Wlo,
                                                 const float* __restrict__ dinv,
                                                 _Float16* __restrict__ H, int N) {
    constexpr int CB = F / 16;
    constexpr int KB = K / 32;
    constexpr int HCH = CB * 64;
    constexpr int CHUNKS = HCH * 2;
    constexpr int CPT = (CHUNKS + 255) / 256;

    __shared__ __align__(16) short Bs[2][CB * 1024];

    const int tid = threadIdx.x;
    const int wid = tid >> 6, lane = tid & 63;
    const int rowf = lane & 15;
    const int kgrp = lane >> 4;
    const long long row0 = (long long)blockIdx.x * 64 + wid * 16;

    f32x4 acc[CB] = {};
    short8 breg[CPT];
    float fvaC[8], fvaN[8];

    auto stage_issue = [&](int kb) {
#pragma unroll
        for (int i = 0; i < CPT; ++i) {
            int c = tid + i * 256;
            if (CHUNKS < 256 && c >= CHUNKS) continue;
            const short* p = (c < HCH) ? (Whi + (size_t)kb * (CB * 512) + (size_t)c * 8)
                                       : (Wlo + (size_t)kb * (CB * 512) + (size_t)(c - HCH) * 8);
            breg[i] = *(const short8*)p;
        }
    };
    auto stage_write = [&](int b) {
#pragma unroll
        for (int i = 0; i < CPT; ++i) {
            int c = tid + i * 256;
            if (CHUNKS < 256 && c >= CHUNKS) continue;
            *(short8*)&Bs[b][(size_t)c * 8] = breg[i];
        }
    };
    auto a_load = [&](float (&dst)[8], int kb) {
        long long r = row0 + rowf;
        if (r < N) {
            const AT* ap = A + (size_t)r * K + kb * 32 + kgrp * 8;
            if constexpr (sizeof(AT) == 4) {
                float4 f0 = ((const float4*)ap)[0];
                float4 f1 = ((const float4*)ap)[1];
                dst[0]=f0.x; dst[1]=f0.y; dst[2]=f0.z; dst[3]=f0.w;
                dst[4]=f1.x; dst[5]=f1.y; dst[6]=f1.z; dst[7]=f1.w;
            } else {
                h16x8 hv = *(const h16x8*)ap;
#pragma unroll
                for (int j = 0; j < 8; ++j) dst[j] = (float)hv[j];
            }
        } else {
#pragma unroll
            for (int j = 0; j < 8; ++j) dst[j] = 0.f;
        }
    };

    stage_issue(0);
    a_load(fvaC, 0);

    for (int kb = 0; kb < KB; ++kb) {
        const int b = kb & 1;
        stage_write(b);
        if (kb + 1 < KB) stage_issue(kb + 1);
        asm volatile("s_waitcnt lgkmcnt(0)" ::: "memory");
        __builtin_amdgcn_s_barrier();
        __builtin_amdgcn_sched_barrier(0);
        if (kb + 1 < KB) a_load(fvaN, kb + 1);

        short8 ahi, alo;
#pragma unroll
        for (int j = 0; j < 8; ++j) {
            BF16Pair p = split_bf16(fvaC[j]);
            ahi[j] = p.hi;
            alo[j] = p.lo;
        }
#pragma unroll
        for (int cb = 0; cb < CB; ++cb) {
            short8 bhi = *(const short8*)&Bs[b][((size_t)cb * 64 + lane) * 8];
            short8 blo = *(const short8*)&Bs[b][CB * 512 + ((size_t)cb * 64 + lane) * 8];
            acc[cb] = __builtin_amdgcn_mfma_f32_16x16x32_bf16(ahi, bhi, acc[cb], 0, 0, 0);
            acc[cb] = __builtin_amdgcn_mfma_f32_16x16x32_bf16(alo, bhi, acc[cb], 0, 0, 0);
            acc[cb] = __builtin_amdgcn_mfma_f32_16x16x32_bf16(ahi, blo, acc[cb], 0, 0, 0);
        }
#pragma unroll
        for (int j = 0; j < 8; ++j) fvaC[j] = fvaN[j];
    }

    const int rsub = (lane >> 4) * 4;
    long long rbase = row0 + rsub;
    float dv[4];
#pragma unroll
    for (int j = 0; j < 4; ++j) dv[j] = (rbase + j < N) ? dinv[rbase + j] : 0.f;
#pragma unroll
    for (int cb = 0; cb < CB; ++cb) {
        int colv = cb * 16 + rowf;
#pragma unroll
        for (int j = 0; j < 4; ++j) {
            long long r = rbase + j;
            if (r < N) H[(size_t)r * F + colv] = (_Float16)(acc[cb][j] * dv[j]);
        }
    }
}

// ---------------- fused CSR aggregation (fp16 gather, fp32 accum) ----------------

template<int F, bool RELU, typename OutT>
__global__ __launch_bounds__(256) void agg_kernel(const _Float16* __restrict__ hs,
                                                  const int* __restrict__ rp,
                                                  const int* __restrict__ col,
                                                  const float* __restrict__ dinv,
                                                  const float* __restrict__ bias,
                                                  OutT* __restrict__ out, int N) {
    constexpr int LPN = F / 8;            // lanes per node, 16B/lane
    constexpr int NPB = 256 / LPN;
    const int tid = threadIdx.x;
    const int lane = tid % LPN;
    const int node = blockIdx.x * NPB + tid / LPN;
    if (node >= N) return;

    const int f0 = lane * 8;
    const _Float16* hbase = hs + f0;

    float acc[8];
    {
        h16x8 sv = *(const h16x8*)(hbase + (size_t)node * F);
#pragma unroll
        for (int v = 0; v < 8; ++v) acc[v] = (float)sv[v];
    }

    int e = rp[node];
    const int e1 = rp[node + 1];
    for (; e + 4 <= e1; e += 4) {
        int s0 = col[e], s1 = col[e + 1], s2 = col[e + 2], s3 = col[e + 3];
        h16x8 v0 = *(const h16x8*)(hbase + (size_t)s0 * F);
        h16x8 v1 = *(const h16x8*)(hbase + (size_t)s1 * F);
        h16x8 v2 = *(const h16x8*)(hbase + (size_t)s2 * F);
        h16x8 v3 = *(const h16x8*)(hbase + (size_t)s3 * F);
#pragma unroll
        for (int v = 0; v < 8; ++v)
            acc[v] += ((float)v0[v] + (float)v1[v]) + ((float)v2[v] + (float)v3[v]);
    }
    for (; e < e1; ++e) {
        h16x8 v0 = *(const h16x8*)(hbase + (size_t)col[e] * F);
#pragma unroll
        for (int v = 0; v < 8; ++v) acc[v] += (float)v0[v];
    }

    const float self = dinv[node];
    OutT* op = out + (size_t)node * F + f0;
    const float* bp = bias + f0;
#pragma unroll
    for (int v = 0; v < 8; ++v) {
        float r = fmaf(acc[v], self, bp[v]);
        if (RELU) r = fmaxf(r, 0.f);
        op[v] = (OutT)r;
    }
}

// ---------------- launcher ----------------

extern "C" void kernel_launch(void* const* d_in, const int* in_sizes, int n_in,
                              void* d_out, int out_size, void* d_ws, size_t ws_size,
                              hipStream_t stream) {
    const float* x  = (const float*)d_in[0];
    const int*   ei = (const int*)d_in[1];
    const float* W1 = (const float*)d_in[2];
    const float* b1 = (const float*)d_in[3];
    const float* W2 = (const float*)d_in[4];
    const float* b2 = (const float*)d_in[5];
    const float* W3 = (const float*)d_in[6];
    const float* b3 = (const float*)d_in[7];
    const float* W4 = (const float*)d_in[8];
    const float* b4 = (const float*)d_in[9];

    const int N = in_sizes[0] / 256;
    const int E = in_sizes[1] / 2;
    const int* src = ei;
    const int* dst = ei + E;

    const int nbuk = ((N - 1) >> BUK_SHIFT) + 1;
    const int nblk = CDIV(E, EPB);

    char* base = (char*)d_ws;
    size_t o = 0;
    auto alloc = [&](size_t bytes) { char* p = base + o; o += (bytes + 255) & ~(size_t)255; return p; };
    int*   rp   = (int*)  alloc(sizeof(int) * (N + 1));
    float* dinv = (float*)alloc(sizeof(float) * N);
    int*   col  = (int*)  alloc(sizeof(int) * E);
    int*   hcnt = (int*)  alloc(sizeof(int) * (size_t)nbuk * nblk);
    unsigned long long* ebuf = (unsigned long long*)alloc(sizeof(unsigned long long) * E);
    short* w1h  = (short*)alloc(sizeof(short) * 256 * 128);
    short* w1l  = (short*)alloc(sizeof(short) * 256 * 128);
    short* w2h  = (short*)alloc(sizeof(short) * 128 * 128);
    short* w2l  = (short*)alloc(sizeof(short) * 128 * 128);
    short* w3h  = (short*)alloc(sizeof(short) * 128 * 64);
    short* w3l  = (short*)alloc(sizeof(short) * 128 * 64);
    short* w4h  = (short*)alloc(sizeof(short) * 64 * 32);
    short* w4l  = (short*)alloc(sizeof(short) * 64 * 32);
    _Float16* hsbuf = (_Float16*)alloc(sizeof(_Float16) * (size_t)N * 128);
    _Float16* zsbuf = (_Float16*)alloc(sizeof(_Float16) * (size_t)N * 128);
    float* out  = (float*)d_out;

    // --- weight prep (split-bf16, fragment-swizzled) ---
    wprep_kernel<256, 128><<<CDIV(256 * 128, 256), 256, 0, stream>>>(W1, w1h, w1l);
    wprep_kernel<128, 128><<<CDIV(128 * 128, 256), 256, 0, stream>>>(W2, w2h, w2l);
    wprep_kernel<128, 64><<<CDIV(128 * 64, 256), 256, 0, stream>>>(W3, w3h, w3l);
    wprep_kernel<64, 32><<<CDIV(64 * 32, 256), 256, 0, stream>>>(W4, w4h, w4l);

    // --- bucketed edge sort ---
    bkt_hist_kernel<<<nblk, 256, 0, stream>>>(dst, hcnt, E, nbuk, nblk);
    scan_flat_kernel<<<1, 1024, 0, stream>>>(hcnt, nbuk * nblk);
    bkt_scatter_kernel<<<nblk, 256, 0, stream>>>(src, dst, hcnt, ebuf, E, nbuk, nblk);

    // --- fused per-bucket CSR build (hist+scan+rp+dinv+fill, no global atomics) ---
    bucket_csr_kernel<<<nbuk, 1024, 0, stream>>>(ebuf, hcnt, rp, dinv, col, E, N, nbuk, nblk);

    const int GG = CDIV(N, 64);  // gemm grid (64 rows/block)

    // --- layer 1 ---
    mfma_gemm<256, 128, float><<<GG, 256, 0, stream>>>(x, w1h, w1l, dinv, hsbuf, N);
    agg_kernel<128, true, _Float16><<<CDIV(N, 16), 256, 0, stream>>>(hsbuf, rp, col, dinv, b1, zsbuf, N);

    // --- layer 2 ---
    mfma_gemm<128, 128, _Float16><<<GG, 256, 0, stream>>>(zsbuf, w2h, w2l, dinv, hsbuf, N);
    agg_kernel<128, true, _Float16><<<CDIV(N, 16), 256, 0, stream>>>(hsbuf, rp, col, dinv, b2, zsbuf, N);

    // --- layer 3 ---
    mfma_gemm<128, 64, _Float16><<<GG, 256, 0, stream>>>(zsbuf, w3h, w3l, dinv, hsbuf, N);
    agg_kernel<64, true, _Float16><<<CDIV(N, 32), 256, 0, stream>>>(hsbuf, rp, col, dinv, b3, zsbuf, N);

    // --- layer 4 ---
    mfma_gemm<64, 32, _Float16><<<GG, 256, 0, stream>>>(zsbuf, w4h, w4l, dinv, hsbuf, N);
    agg_kernel<32, false, float><<<CDIV(N, 64), 256, 0, stream>>>(hsbuf, rp, col, dinv, b4, out, N);
}